// Round 6
// baseline (356.895 us; speedup 1.0000x reference)
//
#include <hip/hip_runtime.h>
#include <math.h>

#define NEG_SLOPE 0.2f
#define BN_EPS 1e-5f
#define BSH 9
#define BMASK 511

typedef __attribute__((ext_vector_type(8))) short short8;
typedef __attribute__((ext_vector_type(4))) float f32x4;

__device__ __forceinline__ float wave_max64(float v) {
  #pragma unroll
  for (int o = 32; o; o >>= 1) v = fmaxf(v, __shfl_xor(v, o, 64));
  return v;
}
__device__ __forceinline__ float wave_sum64(float v) {
  #pragma unroll
  for (int o = 32; o; o >>= 1) v += __shfl_xor(v, o, 64);
  return v;
}

__device__ __forceinline__ unsigned pack2bf(float a, float b) {
  unsigned ua = __float_as_uint(a);
  unsigned ub = __float_as_uint(b);
  ua = ua + 0x7fffu + ((ua >> 16) & 1u);
  ub = ub + 0x7fffu + ((ub >> 16) & 1u);
  return (ua >> 16) | (ub & 0xffff0000u);
}
__device__ __forceinline__ unsigned short bf16of(float a) {
  unsigned ua = __float_as_uint(a);
  ua = ua + 0x7fffu + ((ua >> 16) & 1u);
  return (unsigned short)(ua >> 16);
}
__device__ __forceinline__ float bf_lo(unsigned u) { return __uint_as_float(u << 16); }
__device__ __forceinline__ float bf_hi(unsigned u) { return __uint_as_float(u & 0xffff0000u); }

union U8 { short8 s; uint4 u; };

// ---------------------------------------------------------------------------
// prep: Mext[k][0..7]=W1[k]·att_s per head, [8..15] att_d (layer1)
//       M2ext[k][0]=W2[k]·att_s2, [1]=W2[k]·att_d2 (layer2)
// ---------------------------------------------------------------------------
__global__ void prep_kernel(const float* __restrict__ W1,
                            const float* __restrict__ att_s,
                            const float* __restrict__ att_d,
                            float* __restrict__ Mext,
                            const float* __restrict__ W2,
                            const float* __restrict__ att_s2,
                            const float* __restrict__ att_d2,
                            float* __restrict__ M2ext)
{
  int k = threadIdx.x;   // 0..127
  #pragma unroll
  for (int h = 0; h < 8; ++h) {
    float s = 0.f, d = 0.f;
    #pragma unroll
    for (int c = 0; c < 16; ++c) {
      float w = W1[k * 128 + h * 16 + c];
      s += w * att_s[h * 16 + c];
      d += w * att_d[h * 16 + c];
    }
    Mext[k * 16 + h] = s;
    Mext[k * 16 + 8 + h] = d;
  }
  float s2 = 0.f, d2 = 0.f;
  #pragma unroll
  for (int c = 0; c < 40; ++c) {
    float w = W2[k * 40 + c];
    s2 += w * att_s2[c];
    d2 += w * att_d2[c];
  }
  M2ext[k * 2] = s2;
  M2ext[k * 2 + 1] = d2;
}

// ---------------------------------------------------------------------------
// MFMA layer-1 GEMM: 128 rows/block, 256 cols (W1 | W_skip) over 4 waves.
// ---------------------------------------------------------------------------
__global__ __launch_bounds__(256) void gemm1_kernel(
    const float* __restrict__ X, const float* __restrict__ W1,
    const float* __restrict__ Wsk, const float* __restrict__ bsk,
    const float* __restrict__ Mext,
    unsigned short* __restrict__ h1u, unsigned short* __restrict__ identu,
    float* __restrict__ alpha_s, float* __restrict__ alpha_d, int N)
{
  __shared__ uint4 Asm4[2048];           // 32 KB: [128 rows][128 bf16]
  const int t = threadIdx.x;
  const int l = t & 63, wave = t >> 6;
  const int lx = l & 15, ly = l >> 4;
  const int row0 = blockIdx.x * 128;
  const int wn0 = wave * 64;

  short8 b[4][4];
  short8 b4[4] = {};
  #pragma unroll
  for (int nf = 0; nf < 4; ++nf) {
    int c = wn0 + nf * 16 + lx;
    const float* bp = (c < 128) ? (W1 + c) : (Wsk + c - 128);
    #pragma unroll
    for (int kf = 0; kf < 4; ++kf) {
      int k0 = kf * 32 + ly * 8;
      U8 f;
      f.u.x = pack2bf(bp[(k0 + 0) * 128], bp[(k0 + 1) * 128]);
      f.u.y = pack2bf(bp[(k0 + 2) * 128], bp[(k0 + 3) * 128]);
      f.u.z = pack2bf(bp[(k0 + 4) * 128], bp[(k0 + 5) * 128]);
      f.u.w = pack2bf(bp[(k0 + 6) * 128], bp[(k0 + 7) * 128]);
      b[nf][kf] = f.s;
    }
  }
  if (wave == 0) {
    const float* bp = Mext + lx;
    #pragma unroll
    for (int kf = 0; kf < 4; ++kf) {
      int k0 = kf * 32 + ly * 8;
      U8 f;
      f.u.x = pack2bf(bp[(k0 + 0) * 16], bp[(k0 + 1) * 16]);
      f.u.y = pack2bf(bp[(k0 + 2) * 16], bp[(k0 + 3) * 16]);
      f.u.z = pack2bf(bp[(k0 + 4) * 16], bp[(k0 + 5) * 16]);
      f.u.w = pack2bf(bp[(k0 + 6) * 16], bp[(k0 + 7) * 16]);
      b4[kf] = f.s;
    }
  }

  {
    int rl = t >> 1;
    int half = t & 1;
    int r = row0 + rl;
    const float* xp = X + (size_t)r * 128 + half * 64;
    #pragma unroll
    for (int i = 0; i < 8; ++i) {
      float4 f0 = make_float4(0.f, 0.f, 0.f, 0.f), f1 = f0;
      if (r < N) {
        f0 = *(const float4*)(xp + i * 8);
        f1 = *(const float4*)(xp + i * 8 + 4);
      }
      uint4 u;
      u.x = pack2bf(f0.x, f0.y); u.y = pack2bf(f0.z, f0.w);
      u.z = pack2bf(f1.x, f1.y); u.w = pack2bf(f1.z, f1.w);
      int woff = (rl * 256 + half * 128 + i * 16) ^ ((rl & 7) << 4);
      *(uint4*)((char*)Asm4 + woff) = u;
    }
  }
  __syncthreads();

  float bval[4];
  if (wave >= 2) {
    #pragma unroll
    for (int nf = 0; nf < 4; ++nf) bval[nf] = bsk[(wave - 2) * 64 + nf * 16 + lx];
  }

  for (int mf = 0; mf < 8; ++mf) {
    short8 a[4];
    int rowl = mf * 16 + lx;
    #pragma unroll
    for (int kf = 0; kf < 4; ++kf)
      a[kf] = *(short8*)((char*)Asm4 + ((rowl * 256 + kf * 64 + ly * 16) ^ ((lx & 7) << 4)));

    int rbase = row0 + mf * 16 + ly * 4;

    #pragma unroll
    for (int nf = 0; nf < 4; ++nf) {
      f32x4 acc = {0.f, 0.f, 0.f, 0.f};
      #pragma unroll
      for (int kf = 0; kf < 4; ++kf)
        acc = __builtin_amdgcn_mfma_f32_16x16x32_bf16(a[kf], b[nf][kf], acc, 0, 0, 0);
      if (wave < 2) {
        int c = wn0 + nf * 16 + lx;
        #pragma unroll
        for (int reg = 0; reg < 4; ++reg) {
          int r = rbase + reg;
          if (r < N) h1u[(size_t)r * 128 + c] = bf16of(acc[reg]);
        }
      } else {
        int c = (wave - 2) * 64 + nf * 16 + lx;
        #pragma unroll
        for (int reg = 0; reg < 4; ++reg) {
          int r = rbase + reg;
          if (r < N) identu[(size_t)r * 128 + c] = bf16of(acc[reg] + bval[nf]);
        }
      }
    }

    if (wave == 0) {
      f32x4 acc = {0.f, 0.f, 0.f, 0.f};
      #pragma unroll
      for (int kf = 0; kf < 4; ++kf)
        acc = __builtin_amdgcn_mfma_f32_16x16x32_bf16(a[kf], b4[kf], acc, 0, 0, 0);
      #pragma unroll
      for (int reg = 0; reg < 4; ++reg) {
        int r = rbase + reg;
        if (r < N) {
          if (lx < 8) alpha_s[(size_t)r * 8 + lx] = acc[reg];
          else        alpha_d[(size_t)r * 8 + (lx - 8)] = acc[reg];
        }
      }
    }
  }
}

// ---------------------------------------------------------------------------
// Bucketed 2-pass sort by dst.
// ---------------------------------------------------------------------------
__global__ __launch_bounds__(256) void hist_kernel(
    const int* __restrict__ src, const int* __restrict__ dst,
    int* __restrict__ bcnt, int E, int T, int chunk, int NB)
{
  __shared__ int hist[256];
  const int t = threadIdx.x;
  hist[t] = 0;
  __syncthreads();
  int s0 = blockIdx.x * chunk;
  int s1 = min(s0 + chunk, T);
  for (int i = s0 + t; i < s1; i += 256) {
    int d = (i < E) ? dst[i] : (i - E);
    atomicAdd(&hist[d >> BSH], 1);
  }
  __syncthreads();
  if (t < NB && hist[t]) atomicAdd(&bcnt[t], hist[t]);
}

__global__ __launch_bounds__(256) void bscan_kernel(
    const int* __restrict__ bcnt, int* __restrict__ bbase, int* __restrict__ bcur, int NB)
{
  __shared__ int ps[256];
  const int t = threadIdx.x;
  int c = (t < NB) ? bcnt[t] : 0;
  ps[t] = c;
  __syncthreads();
  for (int d = 1; d < 256; d <<= 1) {
    int u = (t >= d) ? ps[t - d] : 0;
    __syncthreads();
    ps[t] += u;
    __syncthreads();
  }
  int excl = ps[t] - c;
  if (t <= NB) {
    bbase[t] = excl;
    if (t < NB) bcur[t] = excl;
  }
}

__global__ __launch_bounds__(256) void scatterA_kernel(
    const int* __restrict__ src, const int* __restrict__ dst,
    int* __restrict__ bcur, unsigned* __restrict__ pkbuf,
    int E, int T, int chunk, int NB)
{
  __shared__ int hist[256];
  __shared__ int lbase[256];
  __shared__ int lcur[256];
  const int t = threadIdx.x;
  hist[t] = 0;
  __syncthreads();
  int s0 = blockIdx.x * chunk;
  int s1 = min(s0 + chunk, T);
  for (int i = s0 + t; i < s1; i += 256) {
    int d = (i < E) ? dst[i] : (i - E);
    atomicAdd(&hist[d >> BSH], 1);
  }
  __syncthreads();
  if (t < NB) {
    int h = hist[t];
    lbase[t] = h ? atomicAdd(&bcur[t], h) : 0;
    lcur[t] = 0;
  }
  __syncthreads();
  for (int i = s0 + t; i < s1; i += 256) {
    int d, s;
    if (i < E) { d = dst[i]; s = src[i]; } else { d = s = i - E; }
    int b = d >> BSH;
    int p = lbase[b] + atomicAdd(&lcur[b], 1);
    pkbuf[p] = ((unsigned)(d & BMASK) << 17) | (unsigned)s;
  }
}

__global__ __launch_bounds__(256) void passB_kernel(
    const unsigned* __restrict__ pkbuf, const int* __restrict__ bbase,
    int* __restrict__ offs, int* __restrict__ ssrc, int N, int T, int NBlast)
{
  __shared__ int cnt[512];
  __shared__ int ps[256];
  __shared__ int cur[512];
  const int t = threadIdx.x;
  const int b = blockIdx.x;
  const int bs = bbase[b], be = bbase[b + 1];

  cnt[t] = 0; cnt[t + 256] = 0;
  __syncthreads();
  for (int i = bs + t; i < be; i += 256)
    atomicAdd(&cnt[pkbuf[i] >> 17], 1);
  __syncthreads();

  int a = cnt[2 * t], b2 = cnt[2 * t + 1];
  ps[t] = a + b2;
  __syncthreads();
  for (int d = 1; d < 256; d <<= 1) {
    int u = (t >= d) ? ps[t - d] : 0;
    __syncthreads();
    ps[t] += u;
    __syncthreads();
  }
  int excl = ps[t] - (a + b2);
  cur[2 * t] = excl;
  cur[2 * t + 1] = excl + a;
  __syncthreads();

  const int node0 = b << BSH;
  #pragma unroll
  for (int jj = 0; jj < 2; ++jj) {
    int d = t + jj * 256;
    int node = node0 + d;
    if (node < N) offs[node] = bs + cur[d];
  }
  if (b == NBlast && t == 0) offs[N] = T;
  __syncthreads();

  for (int i = bs + t; i < be; i += 256) {
    unsigned pk = pkbuf[i];
    int d = pk >> 17;
    int p = atomicAdd(&cur[d], 1);
    ssrc[bs + p] = (int)(pk & 0x1FFFFu);
  }
}

// ---------------------------------------------------------------------------
// FUSED layer-1 aggregation + GEMM2. Block = 128 nodes, 4 waves x 32 nodes.
// Phase A: per-node gather/softmax/BN/ELU/skip, hpost bf16 -> swizzled LDS.
// Phase B: MFMA h2 = hpost@W2 (+ as2/ad2 via M2ext columns).
// ---------------------------------------------------------------------------
__global__ __launch_bounds__(256) void agg1g2_kernel(
    const int* __restrict__ offs, const int* __restrict__ ssrc,
    const float* __restrict__ as1, const float* __restrict__ ad1,
    const unsigned* __restrict__ h1b,
    const float* __restrict__ bias1, const float* __restrict__ gamma,
    const float* __restrict__ beta, const float* __restrict__ mean,
    const float* __restrict__ var,
    const unsigned* __restrict__ identb,
    const float* __restrict__ W2, const float* __restrict__ M2ext,
    unsigned* __restrict__ h2b, float* __restrict__ as2, float* __restrict__ ad2,
    int N)
{
  __shared__ uint4 Asm4[2048];   // 32 KB swizzled hpost tile [128][128 bf16]
  const int t = threadIdx.x;
  const int l = t & 63, wave = t >> 6;
  const int lx = l & 15, ly = l >> 4;
  const int row0 = blockIdx.x * 128;

  // ---- per-lane channel constants (hoisted out of node loop) ----
  const int h = l >> 3;
  const int c0 = l * 2;
  const float bb0 = bias1[c0], bb1 = bias1[c0 + 1];
  const float sc0 = gamma[c0] * rsqrtf(var[c0] + BN_EPS);
  const float sc1 = gamma[c0 + 1] * rsqrtf(var[c0 + 1] + BN_EPS);
  const float mn0 = mean[c0], mn1 = mean[c0 + 1];
  const float bt0 = beta[c0], bt1 = beta[c0 + 1];

  // ---- Phase A: aggregate 32 nodes per wave ----
  for (int i = 0; i < 32; ++i) {
    const int rl = wave * 32 + i;
    const int n = row0 + rl;
    unsigned pk = 0;
    if (n < N) {
      const float ad = ad1[(unsigned)n * 8u + (unsigned)h];
      const int jb = offs[n], je = offs[n + 1];
      float denom = 0.f, a0 = 0.f, a1 = 0.f;

#define EDGE1(SS) { \
      float e = as1[(unsigned)(SS) * 8u + (unsigned)h] + ad; \
      e = fmaxf(e, NEG_SLOPE * e); \
      float ex = __expf(e); \
      unsigned u = h1b[(unsigned)(SS) * 64u + (unsigned)l]; \
      denom += ex; \
      a0 += ex * bf_lo(u); \
      a1 += ex * bf_hi(u); }

      int j = jb;
      for (; j + 4 <= je; j += 4) {
        int s0 = ssrc[j], s1 = ssrc[j + 1], s2 = ssrc[j + 2], s3 = ssrc[j + 3];
        EDGE1(s0) EDGE1(s1) EDGE1(s2) EDGE1(s3)
      }
      for (; j < je; ++j) { int s = ssrc[j]; EDGE1(s) }
#undef EDGE1

      float inv = 1.f / (denom + 1e-16f);
      unsigned uid = identb[(unsigned)n * 64u + (unsigned)l];
      float o0 = a0 * inv + bb0;
      float o1 = a1 * inv + bb1;
      o0 = (o0 - mn0) * sc0 + bt0;
      o1 = (o1 - mn1) * sc1 + bt1;
      o0 = o0 > 0.f ? o0 : expm1f(o0);
      o1 = o1 > 0.f ? o1 : expm1f(o1);
      o0 += bf_lo(uid); o1 += bf_hi(uid);
      pk = pack2bf(o0, o1);
    }
    int woff = (rl * 256 + l * 4) ^ ((rl & 7) << 4);
    *(unsigned*)((char*)Asm4 + woff) = pk;
  }

  // ---- B fragments (loaded after phase A to keep agg-phase VGPRs low) ----
  short8 b[3][4];
  short8 b4[4];
  {
    #pragma unroll
    for (int nf = 0; nf < 3; ++nf) {
      int col = nf * 16 + lx;
      bool v = col < 40;
      const float* bp = W2 + (v ? col : 0);
      #pragma unroll
      for (int kf = 0; kf < 4; ++kf) {
        int k0 = kf * 32 + ly * 8;
        U8 f;
        if (v) {
          f.u.x = pack2bf(bp[(k0 + 0) * 40], bp[(k0 + 1) * 40]);
          f.u.y = pack2bf(bp[(k0 + 2) * 40], bp[(k0 + 3) * 40]);
          f.u.z = pack2bf(bp[(k0 + 4) * 40], bp[(k0 + 5) * 40]);
          f.u.w = pack2bf(bp[(k0 + 6) * 40], bp[(k0 + 7) * 40]);
        } else {
          f.u = make_uint4(0, 0, 0, 0);
        }
        b[nf][kf] = f.s;
      }
    }
    bool va = lx < 2;
    const float* bp = M2ext + (va ? lx : 0);
    #pragma unroll
    for (int kf = 0; kf < 4; ++kf) {
      int k0 = kf * 32 + ly * 8;
      U8 f;
      if (va) {
        f.u.x = pack2bf(bp[(k0 + 0) * 2], bp[(k0 + 1) * 2]);
        f.u.y = pack2bf(bp[(k0 + 2) * 2], bp[(k0 + 3) * 2]);
        f.u.z = pack2bf(bp[(k0 + 4) * 2], bp[(k0 + 5) * 2]);
        f.u.w = pack2bf(bp[(k0 + 6) * 2], bp[(k0 + 7) * 2]);
      } else {
        f.u = make_uint4(0, 0, 0, 0);
      }
      b4[kf] = f.s;
    }
  }
  __syncthreads();

  // ---- Phase B: MFMA over the LDS tile ----
  #pragma unroll
  for (int i2 = 0; i2 < 2; ++i2) {
    int mf = wave * 2 + i2;
    short8 a[4];
    int rowl = mf * 16 + lx;
    #pragma unroll
    for (int kf = 0; kf < 4; ++kf)
      a[kf] = *(short8*)((char*)Asm4 + ((rowl * 256 + kf * 64 + ly * 16) ^ ((lx & 7) << 4)));

    int rbase = row0 + mf * 16 + ly * 4;

    #pragma unroll
    for (int nf = 0; nf < 3; ++nf) {
      f32x4 acc = {0.f, 0.f, 0.f, 0.f};
      #pragma unroll
      for (int kf = 0; kf < 4; ++kf)
        acc = __builtin_amdgcn_mfma_f32_16x16x32_bf16(a[kf], b[nf][kf], acc, 0, 0, 0);
      int c = nf * 16 + lx;
      #pragma unroll
      for (int reg = 0; reg < 4; ++reg) {
        float v = acc[reg];
        float vp = __shfl_xor(v, 1, 64);
        int r = rbase + reg;
        if (r < N && c < 40 && !(lx & 1))
          h2b[(unsigned)r * 20u + (unsigned)(c >> 1)] = pack2bf(v, vp);
      }
    }
    {
      f32x4 acc = {0.f, 0.f, 0.f, 0.f};
      #pragma unroll
      for (int kf = 0; kf < 4; ++kf)
        acc = __builtin_amdgcn_mfma_f32_16x16x32_bf16(a[kf], b4[kf], acc, 0, 0, 0);
      #pragma unroll
      for (int reg = 0; reg < 4; ++reg) {
        int r = rbase + reg;
        if (r < N) {
          if (lx == 0) as2[r] = acc[reg];
          else if (lx == 1) ad2[r] = acc[reg];
        }
      }
    }
  }
}

// ---------------------------------------------------------------------------
// Layer-2 aggregation + bias2 + fused log_softmax.
// 3 edge-groups of 20 lanes each (lanes 60-63 idle), x2 unrolled.
// ---------------------------------------------------------------------------
__global__ __launch_bounds__(256) void agg2_kernel(
    const int* __restrict__ offs, const int* __restrict__ ssrc,
    const float* __restrict__ as2, const float* __restrict__ ad2,
    const unsigned* __restrict__ h2b, const float* __restrict__ bias2,
    float* __restrict__ outp, int N)
{
  const int w = threadIdx.x >> 6, l = threadIdx.x & 63;
  const int n = blockIdx.x * 4 + w;
  if (n >= N) return;
  const int g = l / 20;            // 0,1,2 (3 for idle lanes)
  const int cl = l - g * 20;       // channel pair 0..19
  const bool act = l < 60;
  const float ad = ad2[n];
  const int jb = offs[n], je = offs[n + 1];

  float denom = 0.f, a0 = 0.f, a1 = 0.f;

#define EDGE2G(JJ) { \
    bool v = act && ((JJ) < je); \
    int s = v ? ssrc[JJ] : 0; \
    float e = as2[s] + ad; \
    e = fmaxf(e, NEG_SLOPE * e); \
    float ex = v ? __expf(e) : 0.f; \
    unsigned u = h2b[(unsigned)s * 20u + (unsigned)cl]; \
    denom += ex; \
    a0 += ex * bf_lo(u); \
    a1 += ex * bf_hi(u); }

  int j = jb;
  for (; j + 6 <= je; j += 6) {
    EDGE2G(j + g)
    EDGE2G(j + 3 + g)
  }
  for (; j < je; j += 3) {
    EDGE2G(j + g)
  }
#undef EDGE2G

  // combine the 3 groups into lanes 0..19
  a0 += __shfl(a0, l + 20, 64) + __shfl(a0, l + 40, 64);
  a1 += __shfl(a1, l + 20, 64) + __shfl(a1, l + 40, 64);
  denom += __shfl(denom, l + 20, 64) + __shfl(denom, l + 40, 64);

  const int lc = l < 20 ? l : 0;
  float inv = 1.f / (denom + 1e-16f);
  float o0 = a0 * inv + bias2[2 * lc];
  float o1 = a1 * inv + bias2[2 * lc + 1];

  float mx = wave_max64(l < 20 ? fmaxf(o0, o1) : -3.4e38f);
  float se = wave_sum64(l < 20 ? __expf(o0 - mx) + __expf(o1 - mx) : 0.f);
  float ls = logf(se);
  if (l < 20)
    *(float2*)&outp[(size_t)n * 40 + 2 * l] = make_float2(o0 - mx - ls, o1 - mx - ls);
}

// ---------------------------------------------------------------------------
extern "C" void kernel_launch(void* const* d_in, const int* in_sizes, int n_in,
                              void* d_out, int out_size, void* d_ws, size_t ws_size,
                              hipStream_t stream)
{
  const float* x        = (const float*)d_in[0];
  const int*   ei       = (const int*)d_in[1];
  const float* W1       = (const float*)d_in[2];
  const float* att_src1 = (const float*)d_in[3];
  const float* att_dst1 = (const float*)d_in[4];
  const float* bias1    = (const float*)d_in[5];
  const float* bn_gamma = (const float*)d_in[6];
  const float* bn_beta  = (const float*)d_in[7];
  const float* bn_mean  = (const float*)d_in[8];
  const float* bn_var   = (const float*)d_in[9];
  const float* W2       = (const float*)d_in[10];
  const float* att_src2 = (const float*)d_in[11];
  const float* att_dst2 = (const float*)d_in[12];
  const float* bias2    = (const float*)d_in[13];
  const float* W_skip   = (const float*)d_in[14];
  const float* b_skip   = (const float*)d_in[15];

  const int N = in_sizes[0] / 128;
  const int E = in_sizes[1] / 2;
  const int T = E + N;
  const int NB = (N + BMASK) >> BSH;

  char* p = (char*)d_ws;
  auto alloc = [&](size_t bytes) { char* q = p; p += (bytes + 255) & ~255ull; return q; };
  unsigned* h1b    = (unsigned*)alloc((size_t)N * 64 * 4);   // bf16 [N][128]
  unsigned* identb = (unsigned*)alloc((size_t)N * 64 * 4);   // bf16 [N][128]
  unsigned* h2b    = (unsigned*)alloc((size_t)N * 20 * 4);   // bf16 [N][40]
  float* as1     = (float*)alloc((size_t)N * 8 * 4);
  float* ad1     = (float*)alloc((size_t)N * 8 * 4);
  float* as2     = (float*)alloc((size_t)N * 4);
  float* ad2     = (float*)alloc((size_t)N * 4);
  float* Mext    = (float*)alloc(128 * 16 * 4);
  float* M2ext   = (float*)alloc(128 * 2 * 4);
  int*   offs    = (int*)alloc((size_t)(N + 1) * 4);
  unsigned* pkbuf= (unsigned*)alloc((size_t)T * 4);
  int*   ssrc    = (int*)alloc((size_t)T * 4);
  int*   bcnt    = (int*)alloc((size_t)(NB + 1) * 4);
  int*   bbase   = (int*)alloc((size_t)(NB + 1) * 4);
  int*   bcur    = (int*)alloc((size_t)NB * 4);

  const int* ei_src = ei;
  const int* ei_dst = ei + E;

  hipMemsetAsync(bcnt, 0, (size_t)(NB + 1) * 4, stream);

  prep_kernel<<<1, 128, 0, stream>>>(W1, att_src1, att_dst1, Mext,
                                     W2, att_src2, att_dst2, M2ext);
  gemm1_kernel<<<(N + 127) / 128, 256, 0, stream>>>(
      x, W1, W_skip, b_skip, Mext,
      (unsigned short*)h1b, (unsigned short*)identb, as1, ad1, N);

  const int NBLK_A = 512;
  const int chunk = (T + NBLK_A - 1) / NBLK_A;
  hist_kernel<<<NBLK_A, 256, 0, stream>>>(ei_src, ei_dst, bcnt, E, T, chunk, NB);
  bscan_kernel<<<1, 256, 0, stream>>>(bcnt, bbase, bcur, NB);
  scatterA_kernel<<<NBLK_A, 256, 0, stream>>>(ei_src, ei_dst, bcur, pkbuf, E, T, chunk, NB);
  passB_kernel<<<NB, 256, 0, stream>>>(pkbuf, bbase, offs, ssrc, N, T, NB - 1);

  agg1g2_kernel<<<(N + 127) / 128, 256, 0, stream>>>(
      offs, ssrc, as1, ad1, h1b,
      bias1, bn_gamma, bn_beta, bn_mean, bn_var,
      identb, W2, M2ext, h2b, as2, ad2, N);

  agg2_kernel<<<(N + 3) / 4, 256, 0, stream>>>(offs, ssrc, as2, ad2, h2b, bias2,
                                               (float*)d_out, N);
}

// Round 7
// 300.385 us; speedup vs baseline: 1.1881x; 1.1881x over previous
//
#include <hip/hip_runtime.h>
#include <math.h>

#define NEG_SLOPE 0.2f
#define BN_EPS 1e-5f
#define BSH 9
#define BMASK 511

typedef __attribute__((ext_vector_type(8))) short short8;
typedef __attribute__((ext_vector_type(4))) float f32x4;

__device__ __forceinline__ float wave_max64(float v) {
  #pragma unroll
  for (int o = 32; o; o >>= 1) v = fmaxf(v, __shfl_xor(v, o, 64));
  return v;
}
__device__ __forceinline__ float wave_sum64(float v) {
  #pragma unroll
  for (int o = 32; o; o >>= 1) v += __shfl_xor(v, o, 64);
  return v;
}

__device__ __forceinline__ unsigned pack2bf(float a, float b) {
  unsigned ua = __float_as_uint(a);
  unsigned ub = __float_as_uint(b);
  ua = ua + 0x7fffu + ((ua >> 16) & 1u);
  ub = ub + 0x7fffu + ((ub >> 16) & 1u);
  return (ua >> 16) | (ub & 0xffff0000u);
}
__device__ __forceinline__ unsigned short bf16of(float a) {
  unsigned ua = __float_as_uint(a);
  ua = ua + 0x7fffu + ((ua >> 16) & 1u);
  return (unsigned short)(ua >> 16);
}
__device__ __forceinline__ float bf_lo(unsigned u) { return __uint_as_float(u << 16); }
__device__ __forceinline__ float bf_hi(unsigned u) { return __uint_as_float(u & 0xffff0000u); }

union U8 { short8 s; uint4 u; };

// ---------------------------------------------------------------------------
// prep: Mext[k][0..7]=W1[k]·att_s per head, [8..15] att_d (layer1)
//       M2ext[k][0]=W2[k]·att_s2, [1]=W2[k]·att_d2 (layer2)
// ---------------------------------------------------------------------------
__global__ void prep_kernel(const float* __restrict__ W1,
                            const float* __restrict__ att_s,
                            const float* __restrict__ att_d,
                            float* __restrict__ Mext,
                            const float* __restrict__ W2,
                            const float* __restrict__ att_s2,
                            const float* __restrict__ att_d2,
                            float* __restrict__ M2ext)
{
  int k = threadIdx.x;   // 0..127
  #pragma unroll
  for (int h = 0; h < 8; ++h) {
    float s = 0.f, d = 0.f;
    #pragma unroll
    for (int c = 0; c < 16; ++c) {
      float w = W1[k * 128 + h * 16 + c];
      s += w * att_s[h * 16 + c];
      d += w * att_d[h * 16 + c];
    }
    Mext[k * 16 + h] = s;
    Mext[k * 16 + 8 + h] = d;
  }
  float s2 = 0.f, d2 = 0.f;
  #pragma unroll
  for (int c = 0; c < 40; ++c) {
    float w = W2[k * 40 + c];
    s2 += w * att_s2[c];
    d2 += w * att_d2[c];
  }
  M2ext[k * 2] = s2;
  M2ext[k * 2 + 1] = d2;
}

// ---------------------------------------------------------------------------
// MFMA layer-1 GEMM: 128 rows/block, 256 cols (W1 | W_skip) over 4 waves.
// ---------------------------------------------------------------------------
__global__ __launch_bounds__(256) void gemm1_kernel(
    const float* __restrict__ X, const float* __restrict__ W1,
    const float* __restrict__ Wsk, const float* __restrict__ bsk,
    const float* __restrict__ Mext,
    unsigned short* __restrict__ h1u, unsigned short* __restrict__ identu,
    float* __restrict__ alpha_s, float* __restrict__ alpha_d, int N)
{
  __shared__ uint4 Asm4[2048];           // 32 KB: [128 rows][128 bf16]
  const int t = threadIdx.x;
  const int l = t & 63, wave = t >> 6;
  const int lx = l & 15, ly = l >> 4;
  const int row0 = blockIdx.x * 128;
  const int wn0 = wave * 64;

  short8 b[4][4];
  short8 b4[4] = {};
  #pragma unroll
  for (int nf = 0; nf < 4; ++nf) {
    int c = wn0 + nf * 16 + lx;
    const float* bp = (c < 128) ? (W1 + c) : (Wsk + c - 128);
    #pragma unroll
    for (int kf = 0; kf < 4; ++kf) {
      int k0 = kf * 32 + ly * 8;
      U8 f;
      f.u.x = pack2bf(bp[(k0 + 0) * 128], bp[(k0 + 1) * 128]);
      f.u.y = pack2bf(bp[(k0 + 2) * 128], bp[(k0 + 3) * 128]);
      f.u.z = pack2bf(bp[(k0 + 4) * 128], bp[(k0 + 5) * 128]);
      f.u.w = pack2bf(bp[(k0 + 6) * 128], bp[(k0 + 7) * 128]);
      b[nf][kf] = f.s;
    }
  }
  if (wave == 0) {
    const float* bp = Mext + lx;
    #pragma unroll
    for (int kf = 0; kf < 4; ++kf) {
      int k0 = kf * 32 + ly * 8;
      U8 f;
      f.u.x = pack2bf(bp[(k0 + 0) * 16], bp[(k0 + 1) * 16]);
      f.u.y = pack2bf(bp[(k0 + 2) * 16], bp[(k0 + 3) * 16]);
      f.u.z = pack2bf(bp[(k0 + 4) * 16], bp[(k0 + 5) * 16]);
      f.u.w = pack2bf(bp[(k0 + 6) * 16], bp[(k0 + 7) * 16]);
      b4[kf] = f.s;
    }
  }

  {
    int rl = t >> 1;
    int half = t & 1;
    int r = row0 + rl;
    const float* xp = X + (size_t)r * 128 + half * 64;
    #pragma unroll
    for (int i = 0; i < 8; ++i) {
      float4 f0 = make_float4(0.f, 0.f, 0.f, 0.f), f1 = f0;
      if (r < N) {
        f0 = *(const float4*)(xp + i * 8);
        f1 = *(const float4*)(xp + i * 8 + 4);
      }
      uint4 u;
      u.x = pack2bf(f0.x, f0.y); u.y = pack2bf(f0.z, f0.w);
      u.z = pack2bf(f1.x, f1.y); u.w = pack2bf(f1.z, f1.w);
      int woff = (rl * 256 + half * 128 + i * 16) ^ ((rl & 7) << 4);
      *(uint4*)((char*)Asm4 + woff) = u;
    }
  }
  __syncthreads();

  float bval[4];
  if (wave >= 2) {
    #pragma unroll
    for (int nf = 0; nf < 4; ++nf) bval[nf] = bsk[(wave - 2) * 64 + nf * 16 + lx];
  }

  for (int mf = 0; mf < 8; ++mf) {
    short8 a[4];
    int rowl = mf * 16 + lx;
    #pragma unroll
    for (int kf = 0; kf < 4; ++kf)
      a[kf] = *(short8*)((char*)Asm4 + ((rowl * 256 + kf * 64 + ly * 16) ^ ((lx & 7) << 4)));

    int rbase = row0 + mf * 16 + ly * 4;

    #pragma unroll
    for (int nf = 0; nf < 4; ++nf) {
      f32x4 acc = {0.f, 0.f, 0.f, 0.f};
      #pragma unroll
      for (int kf = 0; kf < 4; ++kf)
        acc = __builtin_amdgcn_mfma_f32_16x16x32_bf16(a[kf], b[nf][kf], acc, 0, 0, 0);
      if (wave < 2) {
        int c = wn0 + nf * 16 + lx;
        #pragma unroll
        for (int reg = 0; reg < 4; ++reg) {
          int r = rbase + reg;
          if (r < N) h1u[(size_t)r * 128 + c] = bf16of(acc[reg]);
        }
      } else {
        int c = (wave - 2) * 64 + nf * 16 + lx;
        #pragma unroll
        for (int reg = 0; reg < 4; ++reg) {
          int r = rbase + reg;
          if (r < N) identu[(size_t)r * 128 + c] = bf16of(acc[reg] + bval[nf]);
        }
      }
    }

    if (wave == 0) {
      f32x4 acc = {0.f, 0.f, 0.f, 0.f};
      #pragma unroll
      for (int kf = 0; kf < 4; ++kf)
        acc = __builtin_amdgcn_mfma_f32_16x16x32_bf16(a[kf], b4[kf], acc, 0, 0, 0);
      #pragma unroll
      for (int reg = 0; reg < 4; ++reg) {
        int r = rbase + reg;
        if (r < N) {
          if (lx < 8) alpha_s[(size_t)r * 8 + lx] = acc[reg];
          else        alpha_d[(size_t)r * 8 + (lx - 8)] = acc[reg];
        }
      }
    }
  }
}

// ---------------------------------------------------------------------------
// Bucketed 2-pass sort by dst.
// ---------------------------------------------------------------------------
__global__ __launch_bounds__(256) void hist_kernel(
    const int* __restrict__ src, const int* __restrict__ dst,
    int* __restrict__ bcnt, int E, int T, int chunk, int NB)
{
  __shared__ int hist[256];
  const int t = threadIdx.x;
  hist[t] = 0;
  __syncthreads();
  int s0 = blockIdx.x * chunk;
  int s1 = min(s0 + chunk, T);
  for (int i = s0 + t; i < s1; i += 256) {
    int d = (i < E) ? dst[i] : (i - E);
    atomicAdd(&hist[d >> BSH], 1);
  }
  __syncthreads();
  if (t < NB && hist[t]) atomicAdd(&bcnt[t], hist[t]);
}

__global__ __launch_bounds__(256) void bscan_kernel(
    const int* __restrict__ bcnt, int* __restrict__ bbase, int* __restrict__ bcur, int NB)
{
  __shared__ int ps[256];
  const int t = threadIdx.x;
  int c = (t < NB) ? bcnt[t] : 0;
  ps[t] = c;
  __syncthreads();
  for (int d = 1; d < 256; d <<= 1) {
    int u = (t >= d) ? ps[t - d] : 0;
    __syncthreads();
    ps[t] += u;
    __syncthreads();
  }
  int excl = ps[t] - c;
  if (t <= NB) {
    bbase[t] = excl;
    if (t < NB) bcur[t] = excl;
  }
}

__global__ __launch_bounds__(256) void scatterA_kernel(
    const int* __restrict__ src, const int* __restrict__ dst,
    int* __restrict__ bcur, unsigned* __restrict__ pkbuf,
    int E, int T, int chunk, int NB)
{
  __shared__ int hist[256];
  __shared__ int lbase[256];
  __shared__ int lcur[256];
  const int t = threadIdx.x;
  hist[t] = 0;
  __syncthreads();
  int s0 = blockIdx.x * chunk;
  int s1 = min(s0 + chunk, T);
  for (int i = s0 + t; i < s1; i += 256) {
    int d = (i < E) ? dst[i] : (i - E);
    atomicAdd(&hist[d >> BSH], 1);
  }
  __syncthreads();
  if (t < NB) {
    int h = hist[t];
    lbase[t] = h ? atomicAdd(&bcur[t], h) : 0;
    lcur[t] = 0;
  }
  __syncthreads();
  for (int i = s0 + t; i < s1; i += 256) {
    int d, s;
    if (i < E) { d = dst[i]; s = src[i]; } else { d = s = i - E; }
    int b = d >> BSH;
    int p = lbase[b] + atomicAdd(&lcur[b], 1);
    pkbuf[p] = ((unsigned)(d & BMASK) << 17) | (unsigned)s;
  }
}

__global__ __launch_bounds__(256) void passB_kernel(
    const unsigned* __restrict__ pkbuf, const int* __restrict__ bbase,
    int* __restrict__ offs, int* __restrict__ ssrc, int N, int T, int NBlast)
{
  __shared__ int cnt[512];
  __shared__ int ps[256];
  __shared__ int cur[512];
  const int t = threadIdx.x;
  const int b = blockIdx.x;
  const int bs = bbase[b], be = bbase[b + 1];

  cnt[t] = 0; cnt[t + 256] = 0;
  __syncthreads();
  for (int i = bs + t; i < be; i += 256)
    atomicAdd(&cnt[pkbuf[i] >> 17], 1);
  __syncthreads();

  int a = cnt[2 * t], b2 = cnt[2 * t + 1];
  ps[t] = a + b2;
  __syncthreads();
  for (int d = 1; d < 256; d <<= 1) {
    int u = (t >= d) ? ps[t - d] : 0;
    __syncthreads();
    ps[t] += u;
    __syncthreads();
  }
  int excl = ps[t] - (a + b2);
  cur[2 * t] = excl;
  cur[2 * t + 1] = excl + a;
  __syncthreads();

  const int node0 = b << BSH;
  #pragma unroll
  for (int jj = 0; jj < 2; ++jj) {
    int d = t + jj * 256;
    int node = node0 + d;
    if (node < N) offs[node] = bs + cur[d];
  }
  if (b == NBlast && t == 0) offs[N] = T;
  __syncthreads();

  for (int i = bs + t; i < be; i += 256) {
    unsigned pk = pkbuf[i];
    int d = pk >> 17;
    int p = atomicAdd(&cur[d], 1);
    ssrc[bs + p] = (int)(pk & 0x1FFFFu);
  }
}

// ---------------------------------------------------------------------------
// Layer-1 aggregation (single pass). One node per wave, no LDS -> max
// occupancy for the latency-bound gather. Writes h_post as bf16.
// ---------------------------------------------------------------------------
__global__ __launch_bounds__(256) void agg1_kernel(
    const int* __restrict__ offs, const int* __restrict__ ssrc,
    const float* __restrict__ as1, const float* __restrict__ ad1,
    const unsigned* __restrict__ h1b,
    const float* __restrict__ bias1, const float* __restrict__ gamma,
    const float* __restrict__ beta, const float* __restrict__ mean,
    const float* __restrict__ var,
    const unsigned* __restrict__ identb, unsigned* __restrict__ hpostb, int N)
{
  const int w = threadIdx.x >> 6, l = threadIdx.x & 63;
  const int n = blockIdx.x * 4 + w;
  if (n >= N) return;
  const int h = l >> 3;
  const int c0 = l * 2;
  const float ad = ad1[(unsigned)n * 8u + (unsigned)h];
  const int jb = offs[n], je = offs[n + 1];

  // hoisted channel constants
  const float bb0 = bias1[c0], bb1 = bias1[c0 + 1];
  const float sc0 = gamma[c0] * rsqrtf(var[c0] + BN_EPS);
  const float sc1 = gamma[c0 + 1] * rsqrtf(var[c0 + 1] + BN_EPS);
  const float mn0 = mean[c0], mn1 = mean[c0 + 1];
  const float bt0 = beta[c0], bt1 = beta[c0 + 1];

  float denom = 0.f, a0 = 0.f, a1 = 0.f;

#define EDGE1(SS) { \
    float e = as1[(unsigned)(SS) * 8u + (unsigned)h] + ad; \
    e = fmaxf(e, NEG_SLOPE * e); \
    float ex = __expf(e); \
    unsigned u = h1b[(unsigned)(SS) * 64u + (unsigned)l]; \
    denom += ex; \
    a0 += ex * bf_lo(u); \
    a1 += ex * bf_hi(u); }

  int j = jb;
  for (; j + 4 <= je; j += 4) {
    int s0 = ssrc[j], s1 = ssrc[j + 1], s2 = ssrc[j + 2], s3 = ssrc[j + 3];
    EDGE1(s0) EDGE1(s1) EDGE1(s2) EDGE1(s3)
  }
  for (; j < je; ++j) { int s = ssrc[j]; EDGE1(s) }
#undef EDGE1

  float inv = 1.f / (denom + 1e-16f);
  unsigned uid = identb[(unsigned)n * 64u + (unsigned)l];
  float o0 = a0 * inv + bb0;
  float o1 = a1 * inv + bb1;
  o0 = (o0 - mn0) * sc0 + bt0;
  o1 = (o1 - mn1) * sc1 + bt1;
  o0 = o0 > 0.f ? o0 : expm1f(o0);
  o1 = o1 > 0.f ? o1 : expm1f(o1);
  o0 += bf_lo(uid); o1 += bf_hi(uid);
  hpostb[(unsigned)n * 64u + (unsigned)l] = pack2bf(o0, o1);
}

// ---------------------------------------------------------------------------
// MFMA GEMM2, LDS-free: A-fragments loaded as uint4 straight from global
// hpostb (row-contiguous 64B per (lx,row) -> line-coalesced). 128 rows/block,
// 4 waves x 2 m-frags. 3 n-frags of W2 cols + alpha frag via M2ext.
// ---------------------------------------------------------------------------
__global__ __launch_bounds__(256) void gemm2_kernel(
    const unsigned* __restrict__ hpostb, const float* __restrict__ W2,
    const float* __restrict__ M2ext,
    unsigned* __restrict__ h2b, float* __restrict__ as2, float* __restrict__ ad2, int N)
{
  const int t = threadIdx.x;
  const int l = t & 63, wave = t >> 6;
  const int lx = l & 15, ly = l >> 4;
  const int row0 = blockIdx.x * 128;

  // B-frags: W2 cols (3 n-frags) + alpha frag
  short8 b[3][4];
  short8 b4[4];
  {
    #pragma unroll
    for (int nf = 0; nf < 3; ++nf) {
      int col = nf * 16 + lx;
      bool v = col < 40;
      const float* bp = W2 + (v ? col : 0);
      #pragma unroll
      for (int kf = 0; kf < 4; ++kf) {
        int k0 = kf * 32 + ly * 8;
        U8 f;
        if (v) {
          f.u.x = pack2bf(bp[(k0 + 0) * 40], bp[(k0 + 1) * 40]);
          f.u.y = pack2bf(bp[(k0 + 2) * 40], bp[(k0 + 3) * 40]);
          f.u.z = pack2bf(bp[(k0 + 4) * 40], bp[(k0 + 5) * 40]);
          f.u.w = pack2bf(bp[(k0 + 6) * 40], bp[(k0 + 7) * 40]);
        } else {
          f.u = make_uint4(0, 0, 0, 0);
        }
        b[nf][kf] = f.s;
      }
    }
    bool va = lx < 2;
    const float* bp = M2ext + (va ? lx : 0);
    #pragma unroll
    for (int kf = 0; kf < 4; ++kf) {
      int k0 = kf * 32 + ly * 8;
      U8 f;
      if (va) {
        f.u.x = pack2bf(bp[(k0 + 0) * 2], bp[(k0 + 1) * 2]);
        f.u.y = pack2bf(bp[(k0 + 2) * 2], bp[(k0 + 3) * 2]);
        f.u.z = pack2bf(bp[(k0 + 4) * 2], bp[(k0 + 5) * 2]);
        f.u.w = pack2bf(bp[(k0 + 6) * 2], bp[(k0 + 7) * 2]);
      } else {
        f.u = make_uint4(0, 0, 0, 0);
      }
      b4[kf] = f.s;
    }
  }

  #pragma unroll
  for (int i2 = 0; i2 < 2; ++i2) {
    int mf = wave * 2 + i2;
    int arow = row0 + mf * 16 + lx;
    short8 a[4];
    #pragma unroll
    for (int kf = 0; kf < 4; ++kf) {
      U8 f;
      f.u = make_uint4(0, 0, 0, 0);
      if (arow < N)
        f.u = *(const uint4*)(hpostb + (unsigned)arow * 64u + (unsigned)(kf * 16 + ly * 4));
      a[kf] = f.s;
    }

    int rbase = row0 + mf * 16 + ly * 4;

    #pragma unroll
    for (int nf = 0; nf < 3; ++nf) {
      f32x4 acc = {0.f, 0.f, 0.f, 0.f};
      #pragma unroll
      for (int kf = 0; kf < 4; ++kf)
        acc = __builtin_amdgcn_mfma_f32_16x16x32_bf16(a[kf], b[nf][kf], acc, 0, 0, 0);
      int c = nf * 16 + lx;
      #pragma unroll
      for (int reg = 0; reg < 4; ++reg) {
        float v = acc[reg];
        float vp = __shfl_xor(v, 1, 64);
        int r = rbase + reg;
        if (r < N && c < 40 && !(lx & 1))
          h2b[(unsigned)r * 20u + (unsigned)(c >> 1)] = pack2bf(v, vp);
      }
    }
    {
      f32x4 acc = {0.f, 0.f, 0.f, 0.f};
      #pragma unroll
      for (int kf = 0; kf < 4; ++kf)
        acc = __builtin_amdgcn_mfma_f32_16x16x32_bf16(a[kf], b4[kf], acc, 0, 0, 0);
      #pragma unroll
      for (int reg = 0; reg < 4; ++reg) {
        int r = rbase + reg;
        if (r < N) {
          if (lx == 0) as2[r] = acc[reg];
          else if (lx == 1) ad2[r] = acc[reg];
        }
      }
    }
  }
}

// ---------------------------------------------------------------------------
// Layer-2 aggregation + bias2 + fused log_softmax.
// 3 edge-groups of 20 lanes each (lanes 60-63 idle), x2 unrolled.
// ---------------------------------------------------------------------------
__global__ __launch_bounds__(256) void agg2_kernel(
    const int* __restrict__ offs, const int* __restrict__ ssrc,
    const float* __restrict__ as2, const float* __restrict__ ad2,
    const unsigned* __restrict__ h2b, const float* __restrict__ bias2,
    float* __restrict__ outp, int N)
{
  const int w = threadIdx.x >> 6, l = threadIdx.x & 63;
  const int n = blockIdx.x * 4 + w;
  if (n >= N) return;
  const int g = l / 20;            // 0,1,2 (3 for idle lanes)
  const int cl = l - g * 20;       // channel pair 0..19
  const bool act = l < 60;
  const float ad = ad2[n];
  const int jb = offs[n], je = offs[n + 1];

  float denom = 0.f, a0 = 0.f, a1 = 0.f;

#define EDGE2G(JJ) { \
    bool v = act && ((JJ) < je); \
    int s = v ? ssrc[JJ] : 0; \
    float e = as2[s] + ad; \
    e = fmaxf(e, NEG_SLOPE * e); \
    float ex = v ? __expf(e) : 0.f; \
    unsigned u = h2b[(unsigned)s * 20u + (unsigned)cl]; \
    denom += ex; \
    a0 += ex * bf_lo(u); \
    a1 += ex * bf_hi(u); }

  int j = jb;
  for (; j + 6 <= je; j += 6) {
    EDGE2G(j + g)
    EDGE2G(j + 3 + g)
  }
  for (; j < je; j += 3) {
    EDGE2G(j + g)
  }
#undef EDGE2G

  // combine the 3 groups into lanes 0..19
  a0 += __shfl(a0, l + 20, 64) + __shfl(a0, l + 40, 64);
  a1 += __shfl(a1, l + 20, 64) + __shfl(a1, l + 40, 64);
  denom += __shfl(denom, l + 20, 64) + __shfl(denom, l + 40, 64);

  const int lc = l < 20 ? l : 0;
  float inv = 1.f / (denom + 1e-16f);
  float o0 = a0 * inv + bias2[2 * lc];
  float o1 = a1 * inv + bias2[2 * lc + 1];

  float mx = wave_max64(l < 20 ? fmaxf(o0, o1) : -3.4e38f);
  float se = wave_sum64(l < 20 ? __expf(o0 - mx) + __expf(o1 - mx) : 0.f);
  float ls = logf(se);
  if (l < 20)
    *(float2*)&outp[(size_t)n * 40 + 2 * l] = make_float2(o0 - mx - ls, o1 - mx - ls);
}

// ---------------------------------------------------------------------------
extern "C" void kernel_launch(void* const* d_in, const int* in_sizes, int n_in,
                              void* d_out, int out_size, void* d_ws, size_t ws_size,
                              hipStream_t stream)
{
  const float* x        = (const float*)d_in[0];
  const int*   ei       = (const int*)d_in[1];
  const float* W1       = (const float*)d_in[2];
  const float* att_src1 = (const float*)d_in[3];
  const float* att_dst1 = (const float*)d_in[4];
  const float* bias1    = (const float*)d_in[5];
  const float* bn_gamma = (const float*)d_in[6];
  const float* bn_beta  = (const float*)d_in[7];
  const float* bn_mean  = (const float*)d_in[8];
  const float* bn_var   = (const float*)d_in[9];
  const float* W2       = (const float*)d_in[10];
  const float* att_src2 = (const float*)d_in[11];
  const float* att_dst2 = (const float*)d_in[12];
  const float* bias2    = (const float*)d_in[13];
  const float* W_skip   = (const float*)d_in[14];
  const float* b_skip   = (const float*)d_in[15];

  const int N = in_sizes[0] / 128;
  const int E = in_sizes[1] / 2;
  const int T = E + N;
  const int NB = (N + BMASK) >> BSH;

  char* p = (char*)d_ws;
  auto alloc = [&](size_t bytes) { char* q = p; p += (bytes + 255) & ~255ull; return q; };
  unsigned* h1b    = (unsigned*)alloc((size_t)N * 64 * 4);   // bf16 [N][128]
  unsigned* hpostb = (unsigned*)alloc((size_t)N * 64 * 4);   // bf16 [N][128]
  unsigned* identb = (unsigned*)alloc((size_t)N * 64 * 4);   // bf16 [N][128]
  float* as1     = (float*)alloc((size_t)N * 8 * 4);
  float* ad1     = (float*)alloc((size_t)N * 8 * 4);
  float* Mext    = (float*)alloc(128 * 16 * 4);
  float* M2ext   = (float*)alloc(128 * 2 * 4);
  int*   offs    = (int*)alloc((size_t)(N + 1) * 4);
  unsigned* pkbuf= (unsigned*)alloc((size_t)T * 4);
  int*   ssrc    = (int*)alloc((size_t)T * 4);
  int*   bcnt    = (int*)alloc((size_t)(NB + 1) * 4);
  int*   bbase   = (int*)alloc((size_t)(NB + 1) * 4);
  int*   bcur    = (int*)alloc((size_t)NB * 4);
  // layer-2 reuse of dead layer-1 buffers (h1b/as1/ad1 dead after agg1)
  unsigned* h2b = h1b;
  float* as2 = as1;
  float* ad2 = ad1;

  const int* ei_src = ei;
  const int* ei_dst = ei + E;

  hipMemsetAsync(bcnt, 0, (size_t)(NB + 1) * 4, stream);

  prep_kernel<<<1, 128, 0, stream>>>(W1, att_src1, att_dst1, Mext,
                                     W2, att_src2, att_dst2, M2ext);
  gemm1_kernel<<<(N + 127) / 128, 256, 0, stream>>>(
      x, W1, W_skip, b_skip, Mext,
      (unsigned short*)h1b, (unsigned short*)identb, as1, ad1, N);

  const int NBLK_A = 512;
  const int chunk = (T + NBLK_A - 1) / NBLK_A;
  hist_kernel<<<NBLK_A, 256, 0, stream>>>(ei_src, ei_dst, bcnt, E, T, chunk, NB);
  bscan_kernel<<<1, 256, 0, stream>>>(bcnt, bbase, bcur, NB);
  scatterA_kernel<<<NBLK_A, 256, 0, stream>>>(ei_src, ei_dst, bcur, pkbuf, E, T, chunk, NB);
  passB_kernel<<<NB, 256, 0, stream>>>(pkbuf, bbase, offs, ssrc, N, T, NB - 1);

  agg1_kernel<<<(N + 3) / 4, 256, 0, stream>>>(offs, ssrc, as1, ad1, h1b,
                                               bias1, bn_gamma, bn_beta, bn_mean, bn_var,
                                               identb, hpostb, N);
  gemm2_kernel<<<(N + 127) / 128, 256, 0, stream>>>(hpostb, W2, M2ext,
                                                    h2b, as2, ad2, N);
  agg2_kernel<<<(N + 3) / 4, 256, 0, stream>>>(offs, ssrc, as2, ad2, h2b, bias2,
                                               (float*)d_out, N);
}

// Round 8
// 289.633 us; speedup vs baseline: 1.2322x; 1.0371x over previous
//
#include <hip/hip_runtime.h>
#include <math.h>

#define NEG_SLOPE 0.2f
#define BN_EPS 1e-5f
#define BSH 9
#define BMASK 511

typedef __attribute__((ext_vector_type(8))) short short8;
typedef __attribute__((ext_vector_type(4))) float f32x4;

__device__ __forceinline__ float wave_max64(float v) {
  #pragma unroll
  for (int o = 32; o; o >>= 1) v = fmaxf(v, __shfl_xor(v, o, 64));
  return v;
}
__device__ __forceinline__ float wave_sum64(float v) {
  #pragma unroll
  for (int o = 32; o; o >>= 1) v += __shfl_xor(v, o, 64);
  return v;
}

__device__ __forceinline__ unsigned pack2bf(float a, float b) {
  unsigned ua = __float_as_uint(a);
  unsigned ub = __float_as_uint(b);
  ua = ua + 0x7fffu + ((ua >> 16) & 1u);
  ub = ub + 0x7fffu + ((ub >> 16) & 1u);
  return (ua >> 16) | (ub & 0xffff0000u);
}
__device__ __forceinline__ float bf_lo(unsigned u) { return __uint_as_float(u << 16); }
__device__ __forceinline__ float bf_hi(unsigned u) { return __uint_as_float(u & 0xffff0000u); }

union U8 { short8 s; uint4 u; };

// ---------------------------------------------------------------------------
// prep: Mext[k][0..7]=W1[k]·att_s per head, [8..15] att_d (layer1)
//       M2ext[k][0]=W2[k]·att_s2, [1]=W2[k]·att_d2 (layer2)
// ---------------------------------------------------------------------------
__global__ void prep_kernel(const float* __restrict__ W1,
                            const float* __restrict__ att_s,
                            const float* __restrict__ att_d,
                            float* __restrict__ Mext,
                            const float* __restrict__ W2,
                            const float* __restrict__ att_s2,
                            const float* __restrict__ att_d2,
                            float* __restrict__ M2ext)
{
  int k = threadIdx.x;   // 0..127
  #pragma unroll
  for (int h = 0; h < 8; ++h) {
    float s = 0.f, d = 0.f;
    #pragma unroll
    for (int c = 0; c < 16; ++c) {
      float w = W1[k * 128 + h * 16 + c];
      s += w * att_s[h * 16 + c];
      d += w * att_d[h * 16 + c];
    }
    Mext[k * 16 + h] = s;
    Mext[k * 16 + 8 + h] = d;
  }
  float s2 = 0.f, d2 = 0.f;
  #pragma unroll
  for (int c = 0; c < 40; ++c) {
    float w = W2[k * 40 + c];
    s2 += w * att_s2[c];
    d2 += w * att_d2[c];
  }
  M2ext[k * 2] = s2;
  M2ext[k * 2 + 1] = d2;
}

// ---------------------------------------------------------------------------
// MFMA layer-1 GEMM: 128 rows/block, 256 cols (W1 | W_skip) over 4 waves.
// Waves 0,1 -> h1 as fp8 e4m3 (pair-packed ushort stores).
// Waves 2,3 -> ident as bf16 (pair-packed dword stores, +b_skip).
// Wave 0 also emits alphas via Mext B-frag.
// ---------------------------------------------------------------------------
__global__ __launch_bounds__(256) void gemm1_kernel(
    const float* __restrict__ X, const float* __restrict__ W1,
    const float* __restrict__ Wsk, const float* __restrict__ bsk,
    const float* __restrict__ Mext,
    unsigned short* __restrict__ h1f8, unsigned* __restrict__ identb,
    float* __restrict__ alpha_s, float* __restrict__ alpha_d, int N)
{
  __shared__ uint4 Asm4[2048];           // 32 KB: [128 rows][128 bf16]
  const int t = threadIdx.x;
  const int l = t & 63, wave = t >> 6;
  const int lx = l & 15, ly = l >> 4;
  const int row0 = blockIdx.x * 128;
  const int wn0 = wave * 64;

  short8 b[4][4];
  short8 b4[4] = {};
  #pragma unroll
  for (int nf = 0; nf < 4; ++nf) {
    int c = wn0 + nf * 16 + lx;
    const float* bp = (c < 128) ? (W1 + c) : (Wsk + c - 128);
    #pragma unroll
    for (int kf = 0; kf < 4; ++kf) {
      int k0 = kf * 32 + ly * 8;
      U8 f;
      f.u.x = pack2bf(bp[(k0 + 0) * 128], bp[(k0 + 1) * 128]);
      f.u.y = pack2bf(bp[(k0 + 2) * 128], bp[(k0 + 3) * 128]);
      f.u.z = pack2bf(bp[(k0 + 4) * 128], bp[(k0 + 5) * 128]);
      f.u.w = pack2bf(bp[(k0 + 6) * 128], bp[(k0 + 7) * 128]);
      b[nf][kf] = f.s;
    }
  }
  if (wave == 0) {
    const float* bp = Mext + lx;
    #pragma unroll
    for (int kf = 0; kf < 4; ++kf) {
      int k0 = kf * 32 + ly * 8;
      U8 f;
      f.u.x = pack2bf(bp[(k0 + 0) * 16], bp[(k0 + 1) * 16]);
      f.u.y = pack2bf(bp[(k0 + 2) * 16], bp[(k0 + 3) * 16]);
      f.u.z = pack2bf(bp[(k0 + 4) * 16], bp[(k0 + 5) * 16]);
      f.u.w = pack2bf(bp[(k0 + 6) * 16], bp[(k0 + 7) * 16]);
      b4[kf] = f.s;
    }
  }

  {
    int rl = t >> 1;
    int half = t & 1;
    int r = row0 + rl;
    const float* xp = X + (size_t)r * 128 + half * 64;
    #pragma unroll
    for (int i = 0; i < 8; ++i) {
      float4 f0 = make_float4(0.f, 0.f, 0.f, 0.f), f1 = f0;
      if (r < N) {
        f0 = *(const float4*)(xp + i * 8);
        f1 = *(const float4*)(xp + i * 8 + 4);
      }
      uint4 u;
      u.x = pack2bf(f0.x, f0.y); u.y = pack2bf(f0.z, f0.w);
      u.z = pack2bf(f1.x, f1.y); u.w = pack2bf(f1.z, f1.w);
      int woff = (rl * 256 + half * 128 + i * 16) ^ ((rl & 7) << 4);
      *(uint4*)((char*)Asm4 + woff) = u;
    }
  }
  __syncthreads();

  float bval[4];
  if (wave >= 2) {
    #pragma unroll
    for (int nf = 0; nf < 4; ++nf) bval[nf] = bsk[(wave - 2) * 64 + nf * 16 + lx];
  }

  for (int mf = 0; mf < 8; ++mf) {
    short8 a[4];
    int rowl = mf * 16 + lx;
    #pragma unroll
    for (int kf = 0; kf < 4; ++kf)
      a[kf] = *(short8*)((char*)Asm4 + ((rowl * 256 + kf * 64 + ly * 16) ^ ((lx & 7) << 4)));

    int rbase = row0 + mf * 16 + ly * 4;

    #pragma unroll
    for (int nf = 0; nf < 4; ++nf) {
      f32x4 acc = {0.f, 0.f, 0.f, 0.f};
      #pragma unroll
      for (int kf = 0; kf < 4; ++kf)
        acc = __builtin_amdgcn_mfma_f32_16x16x32_bf16(a[kf], b[nf][kf], acc, 0, 0, 0);
      if (wave < 2) {
        int c = wn0 + nf * 16 + lx;       // even-lane pairs (c, c+1)
        #pragma unroll
        for (int reg = 0; reg < 4; ++reg) {
          float v = acc[reg];
          float vp = __shfl_xor(v, 1, 64);
          int r = rbase + reg;
          if (!(lx & 1) && r < N) {
            int u = __builtin_amdgcn_cvt_pk_fp8_f32(v, vp, 0, false);
            *(unsigned short*)((char*)h1f8 + (unsigned)r * 128u + (unsigned)c) =
                (unsigned short)u;
          }
        }
      } else {
        int c = (wave - 2) * 64 + nf * 16 + lx;
        #pragma unroll
        for (int reg = 0; reg < 4; ++reg) {
          float v = acc[reg] + bval[nf];
          float vp = __shfl_xor(v, 1, 64);
          int r = rbase + reg;
          if (!(lx & 1) && r < N)
            identb[(unsigned)r * 64u + (unsigned)(c >> 1)] = pack2bf(v, vp);
        }
      }
    }

    if (wave == 0) {
      f32x4 acc = {0.f, 0.f, 0.f, 0.f};
      #pragma unroll
      for (int kf = 0; kf < 4; ++kf)
        acc = __builtin_amdgcn_mfma_f32_16x16x32_bf16(a[kf], b4[kf], acc, 0, 0, 0);
      #pragma unroll
      for (int reg = 0; reg < 4; ++reg) {
        int r = rbase + reg;
        if (r < N) {
          if (lx < 8) alpha_s[(size_t)r * 8 + lx] = acc[reg];
          else        alpha_d[(size_t)r * 8 + (lx - 8)] = acc[reg];
        }
      }
    }
  }
}

// ---------------------------------------------------------------------------
// Bucketed 2-pass sort by dst.
// ---------------------------------------------------------------------------
__global__ __launch_bounds__(256) void hist_kernel(
    const int* __restrict__ src, const int* __restrict__ dst,
    int* __restrict__ bcnt, int E, int T, int chunk, int NB)
{
  __shared__ int hist[256];
  const int t = threadIdx.x;
  hist[t] = 0;
  __syncthreads();
  int s0 = blockIdx.x * chunk;
  int s1 = min(s0 + chunk, T);
  for (int i = s0 + t; i < s1; i += 256) {
    int d = (i < E) ? dst[i] : (i - E);
    atomicAdd(&hist[d >> BSH], 1);
  }
  __syncthreads();
  if (t < NB && hist[t]) atomicAdd(&bcnt[t], hist[t]);
}

__global__ __launch_bounds__(256) void bscan_kernel(
    const int* __restrict__ bcnt, int* __restrict__ bbase, int* __restrict__ bcur, int NB)
{
  __shared__ int ps[256];
  const int t = threadIdx.x;
  int c = (t < NB) ? bcnt[t] : 0;
  ps[t] = c;
  __syncthreads();
  for (int d = 1; d < 256; d <<= 1) {
    int u = (t >= d) ? ps[t - d] : 0;
    __syncthreads();
    ps[t] += u;
    __syncthreads();
  }
  int excl = ps[t] - c;
  if (t <= NB) {
    bbase[t] = excl;
    if (t < NB) bcur[t] = excl;
  }
}

__global__ __launch_bounds__(256) void scatterA_kernel(
    const int* __restrict__ src, const int* __restrict__ dst,
    int* __restrict__ bcur, unsigned* __restrict__ pkbuf,
    int E, int T, int chunk, int NB)
{
  __shared__ int hist[256];
  __shared__ int lbase[256];
  __shared__ int lcur[256];
  const int t = threadIdx.x;
  hist[t] = 0;
  __syncthreads();
  int s0 = blockIdx.x * chunk;
  int s1 = min(s0 + chunk, T);
  for (int i = s0 + t; i < s1; i += 256) {
    int d = (i < E) ? dst[i] : (i - E);
    atomicAdd(&hist[d >> BSH], 1);
  }
  __syncthreads();
  if (t < NB) {
    int h = hist[t];
    lbase[t] = h ? atomicAdd(&bcur[t], h) : 0;
    lcur[t] = 0;
  }
  __syncthreads();
  for (int i = s0 + t; i < s1; i += 256) {
    int d, s;
    if (i < E) { d = dst[i]; s = src[i]; } else { d = s = i - E; }
    int b = d >> BSH;
    int p = lbase[b] + atomicAdd(&lcur[b], 1);
    pkbuf[p] = ((unsigned)(d & BMASK) << 17) | (unsigned)s;
  }
}

__global__ __launch_bounds__(256) void passB_kernel(
    const unsigned* __restrict__ pkbuf, const int* __restrict__ bbase,
    int* __restrict__ offs, int* __restrict__ ssrc, int N, int T, int NBlast)
{
  __shared__ int cnt[512];
  __shared__ int ps[256];
  __shared__ int cur[512];
  const int t = threadIdx.x;
  const int b = blockIdx.x;
  const int bs = bbase[b], be = bbase[b + 1];

  cnt[t] = 0; cnt[t + 256] = 0;
  __syncthreads();
  for (int i = bs + t; i < be; i += 256)
    atomicAdd(&cnt[pkbuf[i] >> 17], 1);
  __syncthreads();

  int a = cnt[2 * t], b2 = cnt[2 * t + 1];
  ps[t] = a + b2;
  __syncthreads();
  for (int d = 1; d < 256; d <<= 1) {
    int u = (t >= d) ? ps[t - d] : 0;
    __syncthreads();
    ps[t] += u;
    __syncthreads();
  }
  int excl = ps[t] - (a + b2);
  cur[2 * t] = excl;
  cur[2 * t + 1] = excl + a;
  __syncthreads();

  const int node0 = b << BSH;
  #pragma unroll
  for (int jj = 0; jj < 2; ++jj) {
    int d = t + jj * 256;
    int node = node0 + d;
    if (node < N) offs[node] = bs + cur[d];
  }
  if (b == NBlast && t == 0) offs[N] = T;
  __syncthreads();

  for (int i = bs + t; i < be; i += 256) {
    unsigned pk = pkbuf[i];
    int d = pk >> 17;
    int p = atomicAdd(&cur[d], 1);
    ssrc[bs + p] = (int)(pk & 0x1FFFFu);
  }
}

// ---------------------------------------------------------------------------
// Layer-1 aggregation. One node per wave, no LDS. fp8 h1 gather with
// saddr+voffset addressing (1 VALU per address). Writes h_post as bf16.
// ---------------------------------------------------------------------------
__global__ __launch_bounds__(256) void agg1_kernel(
    const int* __restrict__ offs, const int* __restrict__ ssrc,
    const float* __restrict__ as1, const float* __restrict__ ad1,
    const unsigned short* __restrict__ h1f8,
    const float* __restrict__ bias1, const float* __restrict__ gamma,
    const float* __restrict__ beta, const float* __restrict__ mean,
    const float* __restrict__ var,
    const unsigned* __restrict__ identb, unsigned* __restrict__ hpostb, int N)
{
  const int w = threadIdx.x >> 6, l = threadIdx.x & 63;
  const int n = blockIdx.x * 4 + w;
  if (n >= N) return;
  const int h = l >> 3;
  const int c0 = l * 2;
  const unsigned l2 = (unsigned)(l * 2);     // byte offset within fp8 row
  const unsigned h4 = (unsigned)(h * 4);     // byte offset within as1 row
  const float ad = ad1[(unsigned)n * 8u + (unsigned)h];
  const int jb = offs[n], je = offs[n + 1];

  const float bb0 = bias1[c0], bb1 = bias1[c0 + 1];
  const float sc0 = gamma[c0] * rsqrtf(var[c0] + BN_EPS);
  const float sc1 = gamma[c0 + 1] * rsqrtf(var[c0 + 1] + BN_EPS);
  const float mn0 = mean[c0], mn1 = mean[c0 + 1];
  const float bt0 = beta[c0], bt1 = beta[c0 + 1];

  const char* as1c = (const char*)as1;
  const char* h1c = (const char*)h1f8;

  float denom = 0.f, a0 = 0.f, a1 = 0.f;

#define EDGE1(SS) { \
    float e = *(const float*)(as1c + (((unsigned)(SS) << 5) + h4)) + ad; \
    e = fmaxf(e, NEG_SLOPE * e); \
    float ex = __expf(e); \
    unsigned u8 = *(const unsigned short*)(h1c + (((unsigned)(SS) << 7) + l2)); \
    denom += ex; \
    a0 += ex * __builtin_amdgcn_cvt_f32_fp8(u8, 0); \
    a1 += ex * __builtin_amdgcn_cvt_f32_fp8(u8, 1); }

  int j = jb;
  for (; j + 4 <= je; j += 4) {
    int s0 = ssrc[j], s1 = ssrc[j + 1], s2 = ssrc[j + 2], s3 = ssrc[j + 3];
    EDGE1(s0) EDGE1(s1) EDGE1(s2) EDGE1(s3)
  }
  for (; j < je; ++j) { int s = ssrc[j]; EDGE1(s) }
#undef EDGE1

  float inv = 1.f / (denom + 1e-16f);
  unsigned uid = identb[(unsigned)n * 64u + (unsigned)l];
  float o0 = a0 * inv + bb0;
  float o1 = a1 * inv + bb1;
  o0 = (o0 - mn0) * sc0 + bt0;
  o1 = (o1 - mn1) * sc1 + bt1;
  o0 = o0 > 0.f ? o0 : expm1f(o0);
  o1 = o1 > 0.f ? o1 : expm1f(o1);
  o0 += bf_lo(uid); o1 += bf_hi(uid);
  hpostb[(unsigned)n * 64u + (unsigned)l] = pack2bf(o0, o1);
}

// ---------------------------------------------------------------------------
// MFMA GEMM2, LDS-free: A-fragments loaded as uint4 straight from global
// hpostb. 128 rows/block, 4 waves x 2 m-frags. 3 n-frags + alpha frag.
// ---------------------------------------------------------------------------
__global__ __launch_bounds__(256) void gemm2_kernel(
    const unsigned* __restrict__ hpostb, const float* __restrict__ W2,
    const float* __restrict__ M2ext,
    unsigned* __restrict__ h2b, float* __restrict__ as2, float* __restrict__ ad2, int N)
{
  const int t = threadIdx.x;
  const int l = t & 63, wave = t >> 6;
  const int lx = l & 15, ly = l >> 4;
  const int row0 = blockIdx.x * 128;

  short8 b[3][4];
  short8 b4[4];
  {
    #pragma unroll
    for (int nf = 0; nf < 3; ++nf) {
      int col = nf * 16 + lx;
      bool v = col < 40;
      const float* bp = W2 + (v ? col : 0);
      #pragma unroll
      for (int kf = 0; kf < 4; ++kf) {
        int k0 = kf * 32 + ly * 8;
        U8 f;
        if (v) {
          f.u.x = pack2bf(bp[(k0 + 0) * 40], bp[(k0 + 1) * 40]);
          f.u.y = pack2bf(bp[(k0 + 2) * 40], bp[(k0 + 3) * 40]);
          f.u.z = pack2bf(bp[(k0 + 4) * 40], bp[(k0 + 5) * 40]);
          f.u.w = pack2bf(bp[(k0 + 6) * 40], bp[(k0 + 7) * 40]);
        } else {
          f.u = make_uint4(0, 0, 0, 0);
        }
        b[nf][kf] = f.s;
      }
    }
    bool va = lx < 2;
    const float* bp = M2ext + (va ? lx : 0);
    #pragma unroll
    for (int kf = 0; kf < 4; ++kf) {
      int k0 = kf * 32 + ly * 8;
      U8 f;
      if (va) {
        f.u.x = pack2bf(bp[(k0 + 0) * 2], bp[(k0 + 1) * 2]);
        f.u.y = pack2bf(bp[(k0 + 2) * 2], bp[(k0 + 3) * 2]);
        f.u.z = pack2bf(bp[(k0 + 4) * 2], bp[(k0 + 5) * 2]);
        f.u.w = pack2bf(bp[(k0 + 6) * 2], bp[(k0 + 7) * 2]);
      } else {
        f.u = make_uint4(0, 0, 0, 0);
      }
      b4[kf] = f.s;
    }
  }

  #pragma unroll
  for (int i2 = 0; i2 < 2; ++i2) {
    int mf = wave * 2 + i2;
    int arow = row0 + mf * 16 + lx;
    short8 a[4];
    #pragma unroll
    for (int kf = 0; kf < 4; ++kf) {
      U8 f;
      f.u = make_uint4(0, 0, 0, 0);
      if (arow < N)
        f.u = *(const uint4*)(hpostb + (unsigned)arow * 64u + (unsigned)(kf * 16 + ly * 4));
      a[kf] = f.s;
    }

    int rbase = row0 + mf * 16 + ly * 4;

    #pragma unroll
    for (int nf = 0; nf < 3; ++nf) {
      f32x4 acc = {0.f, 0.f, 0.f, 0.f};
      #pragma unroll
      for (int kf = 0; kf < 4; ++kf)
        acc = __builtin_amdgcn_mfma_f32_16x16x32_bf16(a[kf], b[nf][kf], acc, 0, 0, 0);
      int c = nf * 16 + lx;
      #pragma unroll
      for (int reg = 0; reg < 4; ++reg) {
        float v = acc[reg];
        float vp = __shfl_xor(v, 1, 64);
        int r = rbase + reg;
        if (r < N && c < 40 && !(lx & 1))
          h2b[(unsigned)r * 20u + (unsigned)(c >> 1)] = pack2bf(v, vp);
      }
    }
    {
      f32x4 acc = {0.f, 0.f, 0.f, 0.f};
      #pragma unroll
      for (int kf = 0; kf < 4; ++kf)
        acc = __builtin_amdgcn_mfma_f32_16x16x32_bf16(a[kf], b4[kf], acc, 0, 0, 0);
      #pragma unroll
      for (int reg = 0; reg < 4; ++reg) {
        int r = rbase + reg;
        if (r < N) {
          if (lx == 0) as2[r] = acc[reg];
          else if (lx == 1) ad2[r] = acc[reg];
        }
      }
    }
  }
}

// ---------------------------------------------------------------------------
// Layer-2 aggregation + bias2 + fused log_softmax.
// 3 edge-groups of 20 lanes each, x2 unrolled; 32-bit voffset addressing.
// ---------------------------------------------------------------------------
__global__ __launch_bounds__(256) void agg2_kernel(
    const int* __restrict__ offs, const int* __restrict__ ssrc,
    const float* __restrict__ as2, const float* __restrict__ ad2,
    const unsigned* __restrict__ h2b, const float* __restrict__ bias2,
    float* __restrict__ outp, int N)
{
  const int w = threadIdx.x >> 6, l = threadIdx.x & 63;
  const int n = blockIdx.x * 4 + w;
  if (n >= N) return;
  const int g = l / 20;            // 0,1,2 (3 for idle lanes)
  const int cl = l - g * 20;       // channel pair 0..19
  const unsigned cl4 = (unsigned)(cl * 4);
  const bool act = l < 60;
  const float ad = ad2[n];
  const int jb = offs[n], je = offs[n + 1];

  const char* as2c = (const char*)as2;
  const char* h2c = (const char*)h2b;

  float denom = 0.f, a0 = 0.f, a1 = 0.f;

#define EDGE2G(JJ) { \
    bool v = act && ((JJ) < je); \
    unsigned s = v ? (unsigned)ssrc[JJ] : 0u; \
    float e = *(const float*)(as2c + (s << 2)) + ad; \
    e = fmaxf(e, NEG_SLOPE * e); \
    float ex = v ? __expf(e) : 0.f; \
    unsigned u = *(const unsigned*)(h2c + (((s << 2) + s) << 4) + cl4); \
    denom += ex; \
    a0 += ex * bf_lo(u); \
    a1 += ex * bf_hi(u); }

  int j = jb;
  for (; j + 6 <= je; j += 6) {
    EDGE2G(j + g)
    EDGE2G(j + 3 + g)
  }
  for (; j < je; j += 3) {
    EDGE2G(j + g)
  }
#undef EDGE2G

  // combine the 3 groups into lanes 0..19
  a0 += __shfl(a0, l + 20, 64) + __shfl(a0, l + 40, 64);
  a1 += __shfl(a1, l + 20, 64) + __shfl(a1, l + 40, 64);
  denom += __shfl(denom, l + 20, 64) + __shfl(denom, l + 40, 64);

  const int lc = l < 20 ? l : 0;
  float inv = 1.f / (denom + 1e-16f);
  float o0 = a0 * inv + bias2[2 * lc];
  float o1 = a1 * inv + bias2[2 * lc + 1];

  float mx = wave_max64(l < 20 ? fmaxf(o0, o1) : -3.4e38f);
  float se = wave_sum64(l < 20 ? __expf(o0 - mx) + __expf(o1 - mx) : 0.f);
  float ls = logf(se);
  if (l < 20)
    *(float2*)&outp[(size_t)n * 40 + 2 * l] = make_float2(o0 - mx - ls, o1 - mx - ls);
}

// ---------------------------------------------------------------------------
extern "C" void kernel_launch(void* const* d_in, const int* in_sizes, int n_in,
                              void* d_out, int out_size, void* d_ws, size_t ws_size,
                              hipStream_t stream)
{
  const float* x        = (const float*)d_in[0];
  const int*   ei       = (const int*)d_in[1];
  const float* W1       = (const float*)d_in[2];
  const float* att_src1 = (const float*)d_in[3];
  const float* att_dst1 = (const float*)d_in[4];
  const float* bias1    = (const float*)d_in[5];
  const float* bn_gamma = (const float*)d_in[6];
  const float* bn_beta  = (const float*)d_in[7];
  const float* bn_mean  = (const float*)d_in[8];
  const float* bn_var   = (const float*)d_in[9];
  const float* W2       = (const float*)d_in[10];
  const float* att_src2 = (const float*)d_in[11];
  const float* att_dst2 = (const float*)d_in[12];
  const float* bias2    = (const float*)d_in[13];
  const float* W_skip   = (const float*)d_in[14];
  const float* b_skip   = (const float*)d_in[15];

  const int N = in_sizes[0] / 128;
  const int E = in_sizes[1] / 2;
  const int T = E + N;
  const int NB = (N + BMASK) >> BSH;

  char* p = (char*)d_ws;
  auto alloc = [&](size_t bytes) { char* q = p; p += (bytes + 255) & ~255ull; return q; };
  unsigned short* h1f8 = (unsigned short*)alloc((size_t)N * 128);   // fp8 [N][128]
  unsigned* hpostb = (unsigned*)alloc((size_t)N * 64 * 4);          // bf16 [N][128]
  unsigned* identb = (unsigned*)alloc((size_t)N * 64 * 4);          // bf16 [N][128]
  float* as1     = (float*)alloc((size_t)N * 8 * 4);
  float* ad1     = (float*)alloc((size_t)N * 8 * 4);
  float* Mext    = (float*)alloc(128 * 16 * 4);
  float* M2ext   = (float*)alloc(128 * 2 * 4);
  int*   offs    = (int*)alloc((size_t)(N + 1) * 4);
  unsigned* pkbuf= (unsigned*)alloc((size_t)T * 4);
  int*   ssrc    = (int*)alloc((size_t)T * 4);
  int*   bcnt    = (int*)alloc((size_t)(NB + 1) * 4);
  int*   bbase   = (int*)alloc((size_t)(NB + 1) * 4);
  int*   bcur    = (int*)alloc((size_t)NB * 4);
  // layer-2 reuse of dead layer-1 buffers (h1f8/as1/ad1 dead after agg1)
  unsigned* h2b = (unsigned*)h1f8;   // needs N*80 B <= N*128 B
  float* as2 = as1;
  float* ad2 = ad1;

  const int* ei_src = ei;
  const int* ei_dst = ei + E;

  hipMemsetAsync(bcnt, 0, (size_t)(NB + 1) * 4, stream);

  prep_kernel<<<1, 128, 0, stream>>>(W1, att_src1, att_dst1, Mext,
                                     W2, att_src2, att_dst2, M2ext);
  gemm1_kernel<<<(N + 127) / 128, 256, 0, stream>>>(
      x, W1, W_skip, b_skip, Mext,
      h1f8, identb, as1, ad1, N);

  const int NBLK_A = 512;
  const int chunk = (T + NBLK_A - 1) / NBLK_A;
  hist_kernel<<<NBLK_A, 256, 0, stream>>>(ei_src, ei_dst, bcnt, E, T, chunk, NB);
  bscan_kernel<<<1, 256, 0, stream>>>(bcnt, bbase, bcur, NB);
  scatterA_kernel<<<NBLK_A, 256, 0, stream>>>(ei_src, ei_dst, bcur, pkbuf, E, T, chunk, NB);
  passB_kernel<<<NB, 256, 0, stream>>>(pkbuf, bbase, offs, ssrc, N, T, NB - 1);

  agg1_kernel<<<(N + 3) / 4, 256, 0, stream>>>(offs, ssrc, as1, ad1, h1f8,
                                               bias1, bn_gamma, bn_beta, bn_mean, bn_var,
                                               identb, hpostb, N);
  gemm2_kernel<<<(N + 127) / 128, 256, 0, stream>>>(hpostb, W2, M2ext,
                                                    h2b, as2, ad2, N);
  agg2_kernel<<<(N + 3) / 4, 256, 0, stream>>>(offs, ssrc, as2, ad2, h2b, bias2,
                                               (float*)d_out, N);
}

// Round 9
// 280.124 us; speedup vs baseline: 1.2741x; 1.0339x over previous
//
#include <hip/hip_runtime.h>
#include <math.h>

#define NEG_SLOPE 0.2f
#define BN_EPS 1e-5f
#define BSH 9
#define BMASK 511
#define LOG2E 1.44269504088896f

typedef __attribute__((ext_vector_type(8))) short short8;
typedef __attribute__((ext_vector_type(4))) float f32x4;

__device__ __forceinline__ float wave_max64(float v) {
  #pragma unroll
  for (int o = 32; o; o >>= 1) v = fmaxf(v, __shfl_xor(v, o, 64));
  return v;
}
__device__ __forceinline__ float wave_sum64(float v) {
  #pragma unroll
  for (int o = 32; o; o >>= 1) v += __shfl_xor(v, o, 64);
  return v;
}

__device__ __forceinline__ unsigned pack2bf(float a, float b) {
  unsigned ua = __float_as_uint(a);
  unsigned ub = __float_as_uint(b);
  ua = ua + 0x7fffu + ((ua >> 16) & 1u);
  ub = ub + 0x7fffu + ((ub >> 16) & 1u);
  return (ua >> 16) | (ub & 0xffff0000u);
}
__device__ __forceinline__ float bf_lo(unsigned u) { return __uint_as_float(u << 16); }
__device__ __forceinline__ float bf_hi(unsigned u) { return __uint_as_float(u & 0xffff0000u); }

union U8 { short8 s; uint4 u; };

// ---------------------------------------------------------------------------
// prep: Mext[k][0..7]=W1[k]·att_s per head, [8..15] att_d  (PRESCALED by log2e)
//       M2ext[k][0]=W2[k]·att_s2, [1]=W2[k]·att_d2        (PRESCALED by log2e)
// Prescale is exact for the softmax: exp2(log2e*lrelu(x)) == exp(lrelu(x))
// since lrelu commutes with positive scaling.
// ---------------------------------------------------------------------------
__global__ void prep_kernel(const float* __restrict__ W1,
                            const float* __restrict__ att_s,
                            const float* __restrict__ att_d,
                            float* __restrict__ Mext,
                            const float* __restrict__ W2,
                            const float* __restrict__ att_s2,
                            const float* __restrict__ att_d2,
                            float* __restrict__ M2ext)
{
  int k = threadIdx.x;   // 0..127
  #pragma unroll
  for (int h = 0; h < 8; ++h) {
    float s = 0.f, d = 0.f;
    #pragma unroll
    for (int c = 0; c < 16; ++c) {
      float w = W1[k * 128 + h * 16 + c];
      s += w * att_s[h * 16 + c];
      d += w * att_d[h * 16 + c];
    }
    Mext[k * 16 + h] = s * LOG2E;
    Mext[k * 16 + 8 + h] = d * LOG2E;
  }
  float s2 = 0.f, d2 = 0.f;
  #pragma unroll
  for (int c = 0; c < 40; ++c) {
    float w = W2[k * 40 + c];
    s2 += w * att_s2[c];
    d2 += w * att_d2[c];
  }
  M2ext[k * 2] = s2 * LOG2E;
  M2ext[k * 2 + 1] = d2 * LOG2E;
}

// ---------------------------------------------------------------------------
// MFMA layer-1 GEMM: 128 rows/block, 256 cols (W1 | W_skip) over 4 waves.
// Waves 0,1 -> h1 as fp8 e4m3. Waves 2,3 -> ident as bf16 (+b_skip).
// Wave 0 also emits (prescaled) alphas via Mext B-frag.
// ---------------------------------------------------------------------------
__global__ __launch_bounds__(256) void gemm1_kernel(
    const float* __restrict__ X, const float* __restrict__ W1,
    const float* __restrict__ Wsk, const float* __restrict__ bsk,
    const float* __restrict__ Mext,
    unsigned short* __restrict__ h1f8, unsigned* __restrict__ identb,
    float* __restrict__ alpha_s, float* __restrict__ alpha_d, int N)
{
  __shared__ uint4 Asm4[2048];           // 32 KB: [128 rows][128 bf16]
  const int t = threadIdx.x;
  const int l = t & 63, wave = t >> 6;
  const int lx = l & 15, ly = l >> 4;
  const int row0 = blockIdx.x * 128;
  const int wn0 = wave * 64;

  short8 b[4][4];
  short8 b4[4] = {};
  #pragma unroll
  for (int nf = 0; nf < 4; ++nf) {
    int c = wn0 + nf * 16 + lx;
    const float* bp = (c < 128) ? (W1 + c) : (Wsk + c - 128);
    #pragma unroll
    for (int kf = 0; kf < 4; ++kf) {
      int k0 = kf * 32 + ly * 8;
      U8 f;
      f.u.x = pack2bf(bp[(k0 + 0) * 128], bp[(k0 + 1) * 128]);
      f.u.y = pack2bf(bp[(k0 + 2) * 128], bp[(k0 + 3) * 128]);
      f.u.z = pack2bf(bp[(k0 + 4) * 128], bp[(k0 + 5) * 128]);
      f.u.w = pack2bf(bp[(k0 + 6) * 128], bp[(k0 + 7) * 128]);
      b[nf][kf] = f.s;
    }
  }
  if (wave == 0) {
    const float* bp = Mext + lx;
    #pragma unroll
    for (int kf = 0; kf < 4; ++kf) {
      int k0 = kf * 32 + ly * 8;
      U8 f;
      f.u.x = pack2bf(bp[(k0 + 0) * 16], bp[(k0 + 1) * 16]);
      f.u.y = pack2bf(bp[(k0 + 2) * 16], bp[(k0 + 3) * 16]);
      f.u.z = pack2bf(bp[(k0 + 4) * 16], bp[(k0 + 5) * 16]);
      f.u.w = pack2bf(bp[(k0 + 6) * 16], bp[(k0 + 7) * 16]);
      b4[kf] = f.s;
    }
  }

  {
    int rl = t >> 1;
    int half = t & 1;
    int r = row0 + rl;
    const float* xp = X + (size_t)r * 128 + half * 64;
    #pragma unroll
    for (int i = 0; i < 8; ++i) {
      float4 f0 = make_float4(0.f, 0.f, 0.f, 0.f), f1 = f0;
      if (r < N) {
        f0 = *(const float4*)(xp + i * 8);
        f1 = *(const float4*)(xp + i * 8 + 4);
      }
      uint4 u;
      u.x = pack2bf(f0.x, f0.y); u.y = pack2bf(f0.z, f0.w);
      u.z = pack2bf(f1.x, f1.y); u.w = pack2bf(f1.z, f1.w);
      int woff = (rl * 256 + half * 128 + i * 16) ^ ((rl & 7) << 4);
      *(uint4*)((char*)Asm4 + woff) = u;
    }
  }
  __syncthreads();

  float bval[4];
  if (wave >= 2) {
    #pragma unroll
    for (int nf = 0; nf < 4; ++nf) bval[nf] = bsk[(wave - 2) * 64 + nf * 16 + lx];
  }

  for (int mf = 0; mf < 8; ++mf) {
    short8 a[4];
    int rowl = mf * 16 + lx;
    #pragma unroll
    for (int kf = 0; kf < 4; ++kf)
      a[kf] = *(short8*)((char*)Asm4 + ((rowl * 256 + kf * 64 + ly * 16) ^ ((lx & 7) << 4)));

    int rbase = row0 + mf * 16 + ly * 4;

    #pragma unroll
    for (int nf = 0; nf < 4; ++nf) {
      f32x4 acc = {0.f, 0.f, 0.f, 0.f};
      #pragma unroll
      for (int kf = 0; kf < 4; ++kf)
        acc = __builtin_amdgcn_mfma_f32_16x16x32_bf16(a[kf], b[nf][kf], acc, 0, 0, 0);
      if (wave < 2) {
        int c = wn0 + nf * 16 + lx;       // even-lane pairs (c, c+1)
        #pragma unroll
        for (int reg = 0; reg < 4; ++reg) {
          float v = acc[reg];
          float vp = __shfl_xor(v, 1, 64);
          int r = rbase + reg;
          if (!(lx & 1) && r < N) {
            int u = __builtin_amdgcn_cvt_pk_fp8_f32(v, vp, 0, false);
            *(unsigned short*)((char*)h1f8 + (unsigned)r * 128u + (unsigned)c) =
                (unsigned short)u;
          }
        }
      } else {
        int c = (wave - 2) * 64 + nf * 16 + lx;
        #pragma unroll
        for (int reg = 0; reg < 4; ++reg) {
          float v = acc[reg] + bval[nf];
          float vp = __shfl_xor(v, 1, 64);
          int r = rbase + reg;
          if (!(lx & 1) && r < N)
            identb[(unsigned)r * 64u + (unsigned)(c >> 1)] = pack2bf(v, vp);
        }
      }
    }

    if (wave == 0) {
      f32x4 acc = {0.f, 0.f, 0.f, 0.f};
      #pragma unroll
      for (int kf = 0; kf < 4; ++kf)
        acc = __builtin_amdgcn_mfma_f32_16x16x32_bf16(a[kf], b4[kf], acc, 0, 0, 0);
      #pragma unroll
      for (int reg = 0; reg < 4; ++reg) {
        int r = rbase + reg;
        if (r < N) {
          if (lx < 8) alpha_s[(size_t)r * 8 + lx] = acc[reg];
          else        alpha_d[(size_t)r * 8 + (lx - 8)] = acc[reg];
        }
      }
    }
  }
}

// ---------------------------------------------------------------------------
// Bucketed 2-pass sort by dst.
// ---------------------------------------------------------------------------
__global__ __launch_bounds__(256) void hist_kernel(
    const int* __restrict__ src, const int* __restrict__ dst,
    int* __restrict__ bcnt, int E, int T, int chunk, int NB)
{
  __shared__ int hist[256];
  const int t = threadIdx.x;
  hist[t] = 0;
  __syncthreads();
  int s0 = blockIdx.x * chunk;
  int s1 = min(s0 + chunk, T);
  for (int i = s0 + t; i < s1; i += 256) {
    int d = (i < E) ? dst[i] : (i - E);
    atomicAdd(&hist[d >> BSH], 1);
  }
  __syncthreads();
  if (t < NB && hist[t]) atomicAdd(&bcnt[t], hist[t]);
}

__global__ __launch_bounds__(256) void bscan_kernel(
    const int* __restrict__ bcnt, int* __restrict__ bbase, int* __restrict__ bcur, int NB)
{
  __shared__ int ps[256];
  const int t = threadIdx.x;
  int c = (t < NB) ? bcnt[t] : 0;
  ps[t] = c;
  __syncthreads();
  for (int d = 1; d < 256; d <<= 1) {
    int u = (t >= d) ? ps[t - d] : 0;
    __syncthreads();
    ps[t] += u;
    __syncthreads();
  }
  int excl = ps[t] - c;
  if (t <= NB) {
    bbase[t] = excl;
    if (t < NB) bcur[t] = excl;
  }
}

__global__ __launch_bounds__(256) void scatterA_kernel(
    const int* __restrict__ src, const int* __restrict__ dst,
    int* __restrict__ bcur, unsigned* __restrict__ pkbuf,
    int E, int T, int chunk, int NB)
{
  __shared__ int hist[256];
  __shared__ int lbase[256];
  __shared__ int lcur[256];
  const int t = threadIdx.x;
  hist[t] = 0;
  __syncthreads();
  int s0 = blockIdx.x * chunk;
  int s1 = min(s0 + chunk, T);
  for (int i = s0 + t; i < s1; i += 256) {
    int d = (i < E) ? dst[i] : (i - E);
    atomicAdd(&hist[d >> BSH], 1);
  }
  __syncthreads();
  if (t < NB) {
    int h = hist[t];
    lbase[t] = h ? atomicAdd(&bcur[t], h) : 0;
    lcur[t] = 0;
  }
  __syncthreads();
  for (int i = s0 + t; i < s1; i += 256) {
    int d, s;
    if (i < E) { d = dst[i]; s = src[i]; } else { d = s = i - E; }
    int b = d >> BSH;
    int p = lbase[b] + atomicAdd(&lcur[b], 1);
    pkbuf[p] = ((unsigned)(d & BMASK) << 17) | (unsigned)s;
  }
}

__global__ __launch_bounds__(256) void passB_kernel(
    const unsigned* __restrict__ pkbuf, const int* __restrict__ bbase,
    int* __restrict__ offs, int* __restrict__ ssrc, int N, int T, int NBlast)
{
  __shared__ int cnt[512];
  __shared__ int ps[256];
  __shared__ int cur[512];
  const int t = threadIdx.x;
  const int b = blockIdx.x;
  const int bs = bbase[b], be = bbase[b + 1];

  cnt[t] = 0; cnt[t + 256] = 0;
  __syncthreads();
  for (int i = bs + t; i < be; i += 256)
    atomicAdd(&cnt[pkbuf[i] >> 17], 1);
  __syncthreads();

  int a = cnt[2 * t], b2 = cnt[2 * t + 1];
  ps[t] = a + b2;
  __syncthreads();
  for (int d = 1; d < 256; d <<= 1) {
    int u = (t >= d) ? ps[t - d] : 0;
    __syncthreads();
    ps[t] += u;
    __syncthreads();
  }
  int excl = ps[t] - (a + b2);
  cur[2 * t] = excl;
  cur[2 * t + 1] = excl + a;
  __syncthreads();

  const int node0 = b << BSH;
  #pragma unroll
  for (int jj = 0; jj < 2; ++jj) {
    int d = t + jj * 256;
    int node = node0 + d;
    if (node < N) offs[node] = bs + cur[d];
  }
  if (b == NBlast && t == 0) offs[N] = T;
  __syncthreads();

  for (int i = bs + t; i < be; i += 256) {
    unsigned pk = pkbuf[i];
    int d = pk >> 17;
    int p = atomicAdd(&cur[d], 1);
    ssrc[bs + p] = (int)(pk & 0x1FFFFu);
  }
}

// ---------------------------------------------------------------------------
// Layer-1 aggregation, two-phase. One node per wave, no LDS.
// Phase 1: lane (e8=l>>3, hh=l&7) computes edge-weight ew = exp2(lrelu(
//   as1p[s][hh] + ad1p[n][hh])) for 8 edges x 8 heads at once (alphas are
//   prescaled by log2e, so exp2 == exp of the unscaled value).
// Phase 2: per edge k, s broadcast to SGPR via readlane (scalar addressing),
//   ew for my head via ds_bpermute; fp8 h1 row gather + 2 fma.
// Denominators accumulate in phase-1 regs; reduced once at the end.
// ---------------------------------------------------------------------------
__global__ __launch_bounds__(256) void agg1_kernel(
    const int* __restrict__ offs, const int* __restrict__ ssrc,
    const float* __restrict__ as1, const float* __restrict__ ad1,
    const unsigned short* __restrict__ h1f8,
    const float* __restrict__ bias1, const float* __restrict__ gamma,
    const float* __restrict__ beta, const float* __restrict__ mean,
    const float* __restrict__ var,
    const unsigned* __restrict__ identb, unsigned* __restrict__ hpostb, int N)
{
  const int w = threadIdx.x >> 6, l = threadIdx.x & 63;
  const int n = blockIdx.x * 4 + w;
  if (n >= N) return;
  const int e8 = l >> 3;           // phase-1 edge slot
  const int hh = l & 7;            // phase-1 head
  const int h2_4 = (l >> 3) * 4;   // phase-2 head * 4 (bpermute byte idx base)
  const int c0 = l * 2;
  const unsigned l2 = (unsigned)(l * 2);     // byte offset within fp8 row
  const float adp = ad1[(unsigned)n * 8u + (unsigned)hh];   // prescaled
  const int jb = offs[n], je = offs[n + 1];

  const float bb0 = bias1[c0], bb1 = bias1[c0 + 1];
  const float sc0 = gamma[c0] * rsqrtf(var[c0] + BN_EPS);
  const float sc1 = gamma[c0 + 1] * rsqrtf(var[c0 + 1] + BN_EPS);
  const float mn0 = mean[c0], mn1 = mean[c0 + 1];
  const float bt0 = beta[c0], bt1 = beta[c0 + 1];

  const char* h1c = (const char*)h1f8;

  float dsum = 0.f, a0 = 0.f, a1 = 0.f;

#define PHASE2(K, SVEC, EW) { \
    unsigned sk = (unsigned)__builtin_amdgcn_readlane(SVEC, (K) * 8); \
    float ewk = __uint_as_float( \
        __builtin_amdgcn_ds_bpermute(h2_4 + (K) * 32, __float_as_uint(EW))); \
    unsigned u8 = *(const unsigned short*)(h1c + ((size_t)sk << 7) + l2); \
    a0 += ewk * __builtin_amdgcn_cvt_f32_fp8(u8, 0); \
    a1 += ewk * __builtin_amdgcn_cvt_f32_fp8(u8, 1); }

  int j = jb;
  for (; j + 8 <= je; j += 8) {
    int svec = ssrc[j + e8];
    float e = as1[(unsigned)svec * 8u + (unsigned)hh] + adp;
    e = fmaxf(e, NEG_SLOPE * e);
    float ew = exp2f(e);
    dsum += ew;
    PHASE2(0, svec, ew) PHASE2(1, svec, ew) PHASE2(2, svec, ew) PHASE2(3, svec, ew)
    PHASE2(4, svec, ew) PHASE2(5, svec, ew) PHASE2(6, svec, ew) PHASE2(7, svec, ew)
  }
  int rem = je - j;
  if (rem > 0) {
    int jj = j + (e8 < rem ? e8 : 0);
    int svec = ssrc[jj];
    float e = as1[(unsigned)svec * 8u + (unsigned)hh] + adp;
    e = fmaxf(e, NEG_SLOPE * e);
    float ew = (e8 < rem) ? exp2f(e) : 0.f;
    dsum += ew;
    for (int k = 0; k < rem; ++k) {
      unsigned sk = (unsigned)__builtin_amdgcn_readlane(svec, k * 8);
      float ewk = __uint_as_float(
          __builtin_amdgcn_ds_bpermute(h2_4 + (k << 5), __float_as_uint(ew)));
      unsigned u8 = *(const unsigned short*)(h1c + ((size_t)sk << 7) + l2);
      a0 += ewk * __builtin_amdgcn_cvt_f32_fp8(u8, 0);
      a1 += ewk * __builtin_amdgcn_cvt_f32_fp8(u8, 1);
    }
  }
#undef PHASE2

  // denom: reduce over e8 (xor 8,16,32) -> lane has denom[hh]; then transpose
  // so lane l gets denom[l>>3] (read from lane l>>3, whose hh == l>>3).
  dsum += __shfl_xor(dsum, 8, 64);
  dsum += __shfl_xor(dsum, 16, 64);
  dsum += __shfl_xor(dsum, 32, 64);
  float denom = __uint_as_float(
      __builtin_amdgcn_ds_bpermute(h2_4, __float_as_uint(dsum)));

  float inv = 1.f / (denom + 1e-16f);
  unsigned uid = identb[(unsigned)n * 64u + (unsigned)l];
  float o0 = a0 * inv + bb0;
  float o1 = a1 * inv + bb1;
  o0 = (o0 - mn0) * sc0 + bt0;
  o1 = (o1 - mn1) * sc1 + bt1;
  o0 = o0 > 0.f ? o0 : expm1f(o0);
  o1 = o1 > 0.f ? o1 : expm1f(o1);
  o0 += bf_lo(uid); o1 += bf_hi(uid);
  hpostb[(unsigned)n * 64u + (unsigned)l] = pack2bf(o0, o1);
}

// ---------------------------------------------------------------------------
// MFMA GEMM2, LDS-free. h2b rows PADDED to 128 B (32 uints) so the agg2
// gather touches exactly one cache line per edge.
// ---------------------------------------------------------------------------
__global__ __launch_bounds__(256) void gemm2_kernel(
    const unsigned* __restrict__ hpostb, const float* __restrict__ W2,
    const float* __restrict__ M2ext,
    unsigned* __restrict__ h2b, float* __restrict__ as2, float* __restrict__ ad2, int N)
{
  const int t = threadIdx.x;
  const int l = t & 63, wave = t >> 6;
  const int lx = l & 15, ly = l >> 4;
  const int row0 = blockIdx.x * 128;

  short8 b[3][4];
  short8 b4[4];
  {
    #pragma unroll
    for (int nf = 0; nf < 3; ++nf) {
      int col = nf * 16 + lx;
      bool v = col < 40;
      const float* bp = W2 + (v ? col : 0);
      #pragma unroll
      for (int kf = 0; kf < 4; ++kf) {
        int k0 = kf * 32 + ly * 8;
        U8 f;
        if (v) {
          f.u.x = pack2bf(bp[(k0 + 0) * 40], bp[(k0 + 1) * 40]);
          f.u.y = pack2bf(bp[(k0 + 2) * 40], bp[(k0 + 3) * 40]);
          f.u.z = pack2bf(bp[(k0 + 4) * 40], bp[(k0 + 5) * 40]);
          f.u.w = pack2bf(bp[(k0 + 6) * 40], bp[(k0 + 7) * 40]);
        } else {
          f.u = make_uint4(0, 0, 0, 0);
        }
        b[nf][kf] = f.s;
      }
    }
    bool va = lx < 2;
    const float* bp = M2ext + (va ? lx : 0);
    #pragma unroll
    for (int kf = 0; kf < 4; ++kf) {
      int k0 = kf * 32 + ly * 8;
      U8 f;
      if (va) {
        f.u.x = pack2bf(bp[(k0 + 0) * 2], bp[(k0 + 1) * 2]);
        f.u.y = pack2bf(bp[(k0 + 2) * 2], bp[(k0 + 3) * 2]);
        f.u.z = pack2bf(bp[(k0 + 4) * 2], bp[(k0 + 5) * 2]);
        f.u.w = pack2bf(bp[(k0 + 6) * 2], bp[(k0 + 7) * 2]);
      } else {
        f.u = make_uint4(0, 0, 0, 0);
      }
      b4[kf] = f.s;
    }
  }

  #pragma unroll
  for (int i2 = 0; i2 < 2; ++i2) {
    int mf = wave * 2 + i2;
    int arow = row0 + mf * 16 + lx;
    short8 a[4];
    #pragma unroll
    for (int kf = 0; kf < 4; ++kf) {
      U8 f;
      f.u = make_uint4(0, 0, 0, 0);
      if (arow < N)
        f.u = *(const uint4*)(hpostb + (unsigned)arow * 64u + (unsigned)(kf * 16 + ly * 4));
      a[kf] = f.s;
    }

    int rbase = row0 + mf * 16 + ly * 4;

    #pragma unroll
    for (int nf = 0; nf < 3; ++nf) {
      f32x4 acc = {0.f, 0.f, 0.f, 0.f};
      #pragma unroll
      for (int kf = 0; kf < 4; ++kf)
        acc = __builtin_amdgcn_mfma_f32_16x16x32_bf16(a[kf], b[nf][kf], acc, 0, 0, 0);
      int c = nf * 16 + lx;
      #pragma unroll
      for (int reg = 0; reg < 4; ++reg) {
        float v = acc[reg];
        float vp = __shfl_xor(v, 1, 64);
        int r = rbase + reg;
        if (r < N && c < 40 && !(lx & 1))
          h2b[((unsigned)r << 5) + (unsigned)(c >> 1)] = pack2bf(v, vp);
      }
    }
    {
      f32x4 acc = {0.f, 0.f, 0.f, 0.f};
      #pragma unroll
      for (int kf = 0; kf < 4; ++kf)
        acc = __builtin_amdgcn_mfma_f32_16x16x32_bf16(a[kf], b4[kf], acc, 0, 0, 0);
      #pragma unroll
      for (int reg = 0; reg < 4; ++reg) {
        int r = rbase + reg;
        if (r < N) {
          if (lx == 0) as2[r] = acc[reg];
          else if (lx == 1) ad2[r] = acc[reg];
        }
      }
    }
  }
}

// ---------------------------------------------------------------------------
// Layer-2 aggregation + bias2 + fused log_softmax. 3 edge-groups of 20 lanes,
// x2 unrolled; 128-B-aligned h2 rows (one line per edge); exp2 weights.
// ---------------------------------------------------------------------------
__global__ __launch_bounds__(256) void agg2_kernel(
    const int* __restrict__ offs, const int* __restrict__ ssrc,
    const float* __restrict__ as2, const float* __restrict__ ad2,
    const unsigned* __restrict__ h2b, const float* __restrict__ bias2,
    float* __restrict__ outp, int N)
{
  const int w = threadIdx.x >> 6, l = threadIdx.x & 63;
  const int n = blockIdx.x * 4 + w;
  if (n >= N) return;
  const int g = l / 20;            // 0,1,2 (3 for idle lanes)
  const int cl = l - g * 20;       // channel pair 0..19
  const unsigned cl4 = (unsigned)(cl * 4);
  const bool act = l < 60;
  const float ad = ad2[n];         // prescaled
  const int jb = offs[n], je = offs[n + 1];

  const char* as2c = (const char*)as2;
  const char* h2c = (const char*)h2b;

  float denom = 0.f, a0 = 0.f, a1 = 0.f;

#define EDGE2G(JJ) { \
    bool v = act && ((JJ) < je); \
    unsigned s = v ? (unsigned)ssrc[JJ] : 0u; \
    float e = *(const float*)(as2c + (s << 2)) + ad; \
    e = fmaxf(e, NEG_SLOPE * e); \
    float ex = v ? exp2f(e) : 0.f; \
    unsigned u = *(const unsigned*)(h2c + ((size_t)s << 7) + cl4); \
    denom += ex; \
    a0 += ex * bf_lo(u); \
    a1 += ex * bf_hi(u); }

  int j = jb;
  for (; j + 6 <= je; j += 6) {
    EDGE2G(j + g)
    EDGE2G(j + 3 + g)
  }
  for (; j < je; j += 3) {
    EDGE2G(j + g)
  }
#undef EDGE2G

  // combine the 3 groups into lanes 0..19
  a0 += __shfl(a0, l + 20, 64) + __shfl(a0, l + 40, 64);
  a1 += __shfl(a1, l + 20, 64) + __shfl(a1, l + 40, 64);
  denom += __shfl(denom, l + 20, 64) + __shfl(denom, l + 40, 64);

  const int lc = l < 20 ? l : 0;
  float inv = 1.f / (denom + 1e-16f);
  float o0 = a0 * inv + bias2[2 * lc];
  float o1 = a1 * inv + bias2[2 * lc + 1];

  float mx = wave_max64(l < 20 ? fmaxf(o0, o1) : -3.4e38f);
  float se = wave_sum64(l < 20 ? __expf(o0 - mx) + __expf(o1 - mx) : 0.f);
  float ls = logf(se);
  if (l < 20)
    *(float2*)&outp[(size_t)n * 40 + 2 * l] = make_float2(o0 - mx - ls, o1 - mx - ls);
}

// ---------------------------------------------------------------------------
extern "C" void kernel_launch(void* const* d_in, const int* in_sizes, int n_in,
                              void* d_out, int out_size, void* d_ws, size_t ws_size,
                              hipStream_t stream)
{
  const float* x        = (const float*)d_in[0];
  const int*   ei       = (const int*)d_in[1];
  const float* W1       = (const float*)d_in[2];
  const float* att_src1 = (const float*)d_in[3];
  const float* att_dst1 = (const float*)d_in[4];
  const float* bias1    = (const float*)d_in[5];
  const float* bn_gamma = (const float*)d_in[6];
  const float* bn_beta  = (const float*)d_in[7];
  const float* bn_mean  = (const float*)d_in[8];
  const float* bn_var   = (const float*)d_in[9];
  const float* W2       = (const float*)d_in[10];
  const float* att_src2 = (const float*)d_in[11];
  const float* att_dst2 = (const float*)d_in[12];
  const float* bias2    = (const float*)d_in[13];
  const float* W_skip   = (const float*)d_in[14];
  const float* b_skip   = (const float*)d_in[15];

  const int N = in_sizes[0] / 128;
  const int E = in_sizes[1] / 2;
  const int T = E + N;
  const int NB = (N + BMASK) >> BSH;

  char* p = (char*)d_ws;
  auto alloc = [&](size_t bytes) { char* q = p; p += (bytes + 255) & ~255ull; return q; };
  unsigned short* h1f8 = (unsigned short*)alloc((size_t)N * 128);   // fp8 [N][128]
  unsigned* hpostb = (unsigned*)alloc((size_t)N * 64 * 4);          // bf16 [N][128]
  unsigned* identb = (unsigned*)alloc((size_t)N * 64 * 4);          // bf16 [N][128]
  float* as1     = (float*)alloc((size_t)N * 8 * 4);
  float* ad1     = (float*)alloc((size_t)N * 8 * 4);
  float* Mext    = (float*)alloc(128 * 16 * 4);
  float* M2ext   = (float*)alloc(128 * 2 * 4);
  int*   offs    = (int*)alloc((size_t)(N + 1) * 4);
  unsigned* pkbuf= (unsigned*)alloc((size_t)T * 4);
  int*   ssrc    = (int*)alloc((size_t)T * 4);
  int*   bcnt    = (int*)alloc((size_t)(NB + 1) * 4);
  int*   bbase   = (int*)alloc((size_t)(NB + 1) * 4);
  int*   bcur    = (int*)alloc((size_t)NB * 4);
  // layer-2 reuse of dead layer-1 buffers (h1f8/as1/ad1 dead after agg1)
  unsigned* h2b = (unsigned*)h1f8;   // [N][32] uints = N*128 B, exact fit
  float* as2 = as1;
  float* ad2 = ad1;

  const int* ei_src = ei;
  const int* ei_dst = ei + E;

  hipMemsetAsync(bcnt, 0, (size_t)(NB + 1) * 4, stream);

  prep_kernel<<<1, 128, 0, stream>>>(W1, att_src1, att_dst1, Mext,
                                     W2, att_src2, att_dst2, M2ext);
  gemm1_kernel<<<(N + 127) / 128, 256, 0, stream>>>(
      x, W1, W_skip, b_skip, Mext,
      h1f8, identb, as1, ad1, N);

  const int NBLK_A = 512;
  const int chunk = (T + NBLK_A - 1) / NBLK_A;
  hist_kernel<<<NBLK_A, 256, 0, stream>>>(ei_src, ei_dst, bcnt, E, T, chunk, NB);
  bscan_kernel<<<1, 256, 0, stream>>>(bcnt, bbase, bcur, NB);
  scatterA_kernel<<<NBLK_A, 256, 0, stream>>>(ei_src, ei_dst, bcur, pkbuf, E, T, chunk, NB);
  passB_kernel<<<NB, 256, 0, stream>>>(pkbuf, bbase, offs, ssrc, N, T, NB - 1);

  agg1_kernel<<<(N + 3) / 4, 256, 0, stream>>>(offs, ssrc, as1, ad1, h1f8,
                                               bias1, bn_gamma, bn_beta, bn_mean, bn_var,
                                               identb, hpostb, N);
  gemm2_kernel<<<(N + 127) / 128, 256, 0, stream>>>(hpostb, W2, M2ext,
                                                    h2b, as2, ad2, N);
  agg2_kernel<<<(N + 3) / 4, 256, 0, stream>>>(offs, ssrc, as2, ad2, h2b, bias2,
                                               (float*)d_out, N);
}

// Round 10
// 258.381 us; speedup vs baseline: 1.3813x; 1.0841x over previous
//
#include <hip/hip_runtime.h>
#include <math.h>

#define NEG_SLOPE 0.2f
#define BN_EPS 1e-5f
#define BSH 9
#define BMASK 511
#define LOG2E 1.44269504088896f
#define BCAP 12288

typedef __attribute__((ext_vector_type(8))) short short8;
typedef __attribute__((ext_vector_type(4))) float f32x4;

__device__ __forceinline__ float wave_max64(float v) {
  #pragma unroll
  for (int o = 32; o; o >>= 1) v = fmaxf(v, __shfl_xor(v, o, 64));
  return v;
}
__device__ __forceinline__ float wave_sum64(float v) {
  #pragma unroll
  for (int o = 32; o; o >>= 1) v += __shfl_xor(v, o, 64);
  return v;
}

__device__ __forceinline__ unsigned pack2bf(float a, float b) {
  unsigned ua = __float_as_uint(a);
  unsigned ub = __float_as_uint(b);
  ua = ua + 0x7fffu + ((ua >> 16) & 1u);
  ub = ub + 0x7fffu + ((ub >> 16) & 1u);
  return (ua >> 16) | (ub & 0xffff0000u);
}
__device__ __forceinline__ float bf_lo(unsigned u) { return __uint_as_float(u << 16); }
__device__ __forceinline__ float bf_hi(unsigned u) { return __uint_as_float(u & 0xffff0000u); }

union U8 { short8 s; uint4 u; };

// ---------------------------------------------------------------------------
// prep: Mext[k][0..7]=W1[k]·att_s per head, [8..15] att_d  (PRESCALED by log2e)
//       M2ext[k][0]=W2[k]·att_s2, [1]=W2[k]·att_d2        (PRESCALED by log2e)
// ---------------------------------------------------------------------------
__global__ void prep_kernel(const float* __restrict__ W1,
                            const float* __restrict__ att_s,
                            const float* __restrict__ att_d,
                            float* __restrict__ Mext,
                            const float* __restrict__ W2,
                            const float* __restrict__ att_s2,
                            const float* __restrict__ att_d2,
                            float* __restrict__ M2ext)
{
  int k = threadIdx.x;   // 0..127
  #pragma unroll
  for (int h = 0; h < 8; ++h) {
    float s = 0.f, d = 0.f;
    #pragma unroll
    for (int c = 0; c < 16; ++c) {
      float w = W1[k * 128 + h * 16 + c];
      s += w * att_s[h * 16 + c];
      d += w * att_d[h * 16 + c];
    }
    Mext[k * 16 + h] = s * LOG2E;
    Mext[k * 16 + 8 + h] = d * LOG2E;
  }
  float s2 = 0.f, d2 = 0.f;
  #pragma unroll
  for (int c = 0; c < 40; ++c) {
    float w = W2[k * 40 + c];
    s2 += w * att_s2[c];
    d2 += w * att_d2[c];
  }
  M2ext[k * 2] = s2 * LOG2E;
  M2ext[k * 2 + 1] = d2 * LOG2E;
}

// ---------------------------------------------------------------------------
// FUSED gemm1 + scatterA. Blocks [0,G1) run the MFMA layer-1 GEMM
// (independent of the sort); blocks [G1, G1+512) run the bucket scatter
// (fixed-capacity buckets, zeroed global counters, no hist/scan needed).
// ---------------------------------------------------------------------------
__global__ __launch_bounds__(256) void gemm1_scatter_kernel(
    // gemm1 args
    const float* __restrict__ X, const float* __restrict__ W1,
    const float* __restrict__ Wsk, const float* __restrict__ bsk,
    const float* __restrict__ Mext,
    unsigned short* __restrict__ h1f8, unsigned* __restrict__ identb,
    float* __restrict__ alpha_s, float* __restrict__ alpha_d, int N,
    // scatter args
    const int* __restrict__ esrc, const int* __restrict__ edst,
    int* __restrict__ bcur, unsigned* __restrict__ pkbuf,
    int E, int T, int chunk, int NB, int G1)
{
  __shared__ uint4 Asm4[2048];           // 32 KB (gemm1 tile / scatter scratch)
  const int t = threadIdx.x;

  if ((int)blockIdx.x >= G1) {
    // -------------------- scatter path --------------------
    int* hist  = (int*)Asm4;
    int* lbase = hist + 256;
    int* lcur  = hist + 512;
    const int bid = (int)blockIdx.x - G1;
    hist[t] = 0;
    __syncthreads();
    int s0 = bid * chunk;
    int s1 = min(s0 + chunk, T);
    for (int i = s0 + t; i < s1; i += 256) {
      int d = (i < E) ? edst[i] : (i - E);
      atomicAdd(&hist[d >> BSH], 1);
    }
    __syncthreads();
    if (t < NB) {
      int h = hist[t];
      lbase[t] = t * BCAP + (h ? atomicAdd(&bcur[t], h) : 0);
      lcur[t] = 0;
    }
    __syncthreads();
    for (int i = s0 + t; i < s1; i += 256) {
      int d, s;
      if (i < E) { d = edst[i]; s = esrc[i]; } else { d = s = i - E; }
      int b = d >> BSH;
      int p = lbase[b] + atomicAdd(&lcur[b], 1);
      pkbuf[p] = ((unsigned)(d & BMASK) << 17) | (unsigned)s;
    }
    return;
  }

  // -------------------- gemm1 path --------------------
  const int l = t & 63, wave = t >> 6;
  const int lx = l & 15, ly = l >> 4;
  const int row0 = blockIdx.x * 128;
  const int wn0 = wave * 64;

  short8 b[4][4];
  short8 b4[4] = {};
  #pragma unroll
  for (int nf = 0; nf < 4; ++nf) {
    int c = wn0 + nf * 16 + lx;
    const float* bp = (c < 128) ? (W1 + c) : (Wsk + c - 128);
    #pragma unroll
    for (int kf = 0; kf < 4; ++kf) {
      int k0 = kf * 32 + ly * 8;
      U8 f;
      f.u.x = pack2bf(bp[(k0 + 0) * 128], bp[(k0 + 1) * 128]);
      f.u.y = pack2bf(bp[(k0 + 2) * 128], bp[(k0 + 3) * 128]);
      f.u.z = pack2bf(bp[(k0 + 4) * 128], bp[(k0 + 5) * 128]);
      f.u.w = pack2bf(bp[(k0 + 6) * 128], bp[(k0 + 7) * 128]);
      b[nf][kf] = f.s;
    }
  }
  if (wave == 0) {
    const float* bp = Mext + lx;
    #pragma unroll
    for (int kf = 0; kf < 4; ++kf) {
      int k0 = kf * 32 + ly * 8;
      U8 f;
      f.u.x = pack2bf(bp[(k0 + 0) * 16], bp[(k0 + 1) * 16]);
      f.u.y = pack2bf(bp[(k0 + 2) * 16], bp[(k0 + 3) * 16]);
      f.u.z = pack2bf(bp[(k0 + 4) * 16], bp[(k0 + 5) * 16]);
      f.u.w = pack2bf(bp[(k0 + 6) * 16], bp[(k0 + 7) * 16]);
      b4[kf] = f.s;
    }
  }

  {
    int rl = t >> 1;
    int half = t & 1;
    int r = row0 + rl;
    const float* xp = X + (size_t)r * 128 + half * 64;
    #pragma unroll
    for (int i = 0; i < 8; ++i) {
      float4 f0 = make_float4(0.f, 0.f, 0.f, 0.f), f1 = f0;
      if (r < N) {
        f0 = *(const float4*)(xp + i * 8);
        f1 = *(const float4*)(xp + i * 8 + 4);
      }
      uint4 u;
      u.x = pack2bf(f0.x, f0.y); u.y = pack2bf(f0.z, f0.w);
      u.z = pack2bf(f1.x, f1.y); u.w = pack2bf(f1.z, f1.w);
      int woff = (rl * 256 + half * 128 + i * 16) ^ ((rl & 7) << 4);
      *(uint4*)((char*)Asm4 + woff) = u;
    }
  }
  __syncthreads();

  float bval[4];
  if (wave >= 2) {
    #pragma unroll
    for (int nf = 0; nf < 4; ++nf) bval[nf] = bsk[(wave - 2) * 64 + nf * 16 + lx];
  }

  for (int mf = 0; mf < 8; ++mf) {
    short8 a[4];
    int rowl = mf * 16 + lx;
    #pragma unroll
    for (int kf = 0; kf < 4; ++kf)
      a[kf] = *(short8*)((char*)Asm4 + ((rowl * 256 + kf * 64 + ly * 16) ^ ((lx & 7) << 4)));

    int rbase = row0 + mf * 16 + ly * 4;

    #pragma unroll
    for (int nf = 0; nf < 4; ++nf) {
      f32x4 acc = {0.f, 0.f, 0.f, 0.f};
      #pragma unroll
      for (int kf = 0; kf < 4; ++kf)
        acc = __builtin_amdgcn_mfma_f32_16x16x32_bf16(a[kf], b[nf][kf], acc, 0, 0, 0);
      if (wave < 2) {
        int c = wn0 + nf * 16 + lx;       // even-lane pairs (c, c+1)
        #pragma unroll
        for (int reg = 0; reg < 4; ++reg) {
          float v = acc[reg];
          float vp = __shfl_xor(v, 1, 64);
          int r = rbase + reg;
          if (!(lx & 1) && r < N) {
            int u = __builtin_amdgcn_cvt_pk_fp8_f32(v, vp, 0, false);
            *(unsigned short*)((char*)h1f8 + (unsigned)r * 128u + (unsigned)c) =
                (unsigned short)u;
          }
        }
      } else {
        int c = (wave - 2) * 64 + nf * 16 + lx;
        #pragma unroll
        for (int reg = 0; reg < 4; ++reg) {
          float v = acc[reg] + bval[nf];
          float vp = __shfl_xor(v, 1, 64);
          int r = rbase + reg;
          if (!(lx & 1) && r < N)
            identb[(unsigned)r * 64u + (unsigned)(c >> 1)] = pack2bf(v, vp);
        }
      }
    }

    if (wave == 0) {
      f32x4 acc = {0.f, 0.f, 0.f, 0.f};
      #pragma unroll
      for (int kf = 0; kf < 4; ++kf)
        acc = __builtin_amdgcn_mfma_f32_16x16x32_bf16(a[kf], b4[kf], acc, 0, 0, 0);
      #pragma unroll
      for (int reg = 0; reg < 4; ++reg) {
        int r = rbase + reg;
        if (r < N) {
          if (lx < 8) alpha_s[(size_t)r * 8 + lx] = acc[reg];
          else        alpha_d[(size_t)r * 8 + (lx - 8)] = acc[reg];
        }
      }
    }
  }
}

// ---------------------------------------------------------------------------
// passB: one block per bucket (fixed base b*BCAP, count from bcur).
// Counting sort of <=512 dst values; emits starts/ends + sorted ssrc.
// ---------------------------------------------------------------------------
__global__ __launch_bounds__(256) void passB_kernel(
    const unsigned* __restrict__ pkbuf, const int* __restrict__ bcnt,
    int* __restrict__ starts, int* __restrict__ ends,
    int* __restrict__ ssrc, int N)
{
  __shared__ int cnt[512];
  __shared__ int ps[256];
  __shared__ int cur[512];
  const int t = threadIdx.x;
  const int b = blockIdx.x;
  const int bs = b * BCAP;
  const int be = bs + bcnt[b];

  cnt[t] = 0; cnt[t + 256] = 0;
  __syncthreads();
  for (int i = bs + t; i < be; i += 256)
    atomicAdd(&cnt[pkbuf[i] >> 17], 1);
  __syncthreads();

  int a = cnt[2 * t], b2 = cnt[2 * t + 1];
  ps[t] = a + b2;
  __syncthreads();
  for (int d = 1; d < 256; d <<= 1) {
    int u = (t >= d) ? ps[t - d] : 0;
    __syncthreads();
    ps[t] += u;
    __syncthreads();
  }
  int excl = ps[t] - (a + b2);
  cur[2 * t] = excl;
  cur[2 * t + 1] = excl + a;
  __syncthreads();

  const int node0 = b << BSH;
  {
    int n0 = node0 + 2 * t, n1 = node0 + 2 * t + 1;
    if (n0 < N) { starts[n0] = bs + cur[2 * t];     ends[n0] = bs + cur[2 * t] + a; }
    if (n1 < N) { starts[n1] = bs + cur[2 * t + 1]; ends[n1] = bs + cur[2 * t + 1] + b2; }
  }
  __syncthreads();

  for (int i = bs + t; i < be; i += 256) {
    unsigned pk = pkbuf[i];
    int d = pk >> 17;
    int p = atomicAdd(&cur[d], 1);
    ssrc[bs + p] = (int)(pk & 0x1FFFFu);
  }
}

// ---------------------------------------------------------------------------
// Layer-1 aggregation, two-phase, 16-deep gather pipeline.
// ---------------------------------------------------------------------------
__global__ __launch_bounds__(256) void agg1_kernel(
    const int* __restrict__ starts, const int* __restrict__ ends,
    const int* __restrict__ ssrc,
    const float* __restrict__ as1, const float* __restrict__ ad1,
    const unsigned short* __restrict__ h1f8,
    const float* __restrict__ bias1, const float* __restrict__ gamma,
    const float* __restrict__ beta, const float* __restrict__ mean,
    const float* __restrict__ var,
    const unsigned* __restrict__ identb, unsigned* __restrict__ hpostb, int N)
{
  const int w = threadIdx.x >> 6, l = threadIdx.x & 63;
  const int n = blockIdx.x * 4 + w;
  if (n >= N) return;
  const int e8 = l >> 3;           // phase-1 edge slot
  const int hh = l & 7;            // phase-1 head
  const int h2_4 = (l >> 3) * 4;   // phase-2 head*4 (bpermute byte idx)
  const int c0 = l * 2;
  const unsigned l2 = (unsigned)(l * 2);
  const float adp = ad1[(unsigned)n * 8u + (unsigned)hh];
  const int jb = starts[n], je = ends[n];

  const float bb0 = bias1[c0], bb1 = bias1[c0 + 1];
  const float sc0 = gamma[c0] * rsqrtf(var[c0] + BN_EPS);
  const float sc1 = gamma[c0 + 1] * rsqrtf(var[c0 + 1] + BN_EPS);
  const float mn0 = mean[c0], mn1 = mean[c0 + 1];
  const float bt0 = beta[c0], bt1 = beta[c0 + 1];

  const char* h1c = (const char*)h1f8;

  float dsum = 0.f, a0 = 0.f, a1 = 0.f;

#define PHASE2(K, SVEC, EW) { \
    unsigned sk = (unsigned)__builtin_amdgcn_readlane(SVEC, (K) * 8); \
    float ewk = __uint_as_float( \
        __builtin_amdgcn_ds_bpermute(h2_4 + (K) * 32, __float_as_uint(EW))); \
    unsigned u8 = *(const unsigned short*)(h1c + ((size_t)sk << 7) + l2); \
    a0 += ewk * __builtin_amdgcn_cvt_f32_fp8(u8, 0); \
    a1 += ewk * __builtin_amdgcn_cvt_f32_fp8(u8, 1); }

  int j = jb;
  for (; j + 16 <= je; j += 16) {
    int sv0 = ssrc[j + e8];
    int sv1 = ssrc[j + 8 + e8];
    float e0 = as1[(unsigned)sv0 * 8u + (unsigned)hh] + adp;
    e0 = fmaxf(e0, NEG_SLOPE * e0);
    float ew0 = exp2f(e0);
    float e1 = as1[(unsigned)sv1 * 8u + (unsigned)hh] + adp;
    e1 = fmaxf(e1, NEG_SLOPE * e1);
    float ew1 = exp2f(e1);
    dsum += ew0 + ew1;
    PHASE2(0, sv0, ew0) PHASE2(1, sv0, ew0) PHASE2(2, sv0, ew0) PHASE2(3, sv0, ew0)
    PHASE2(4, sv0, ew0) PHASE2(5, sv0, ew0) PHASE2(6, sv0, ew0) PHASE2(7, sv0, ew0)
    PHASE2(0, sv1, ew1) PHASE2(1, sv1, ew1) PHASE2(2, sv1, ew1) PHASE2(3, sv1, ew1)
    PHASE2(4, sv1, ew1) PHASE2(5, sv1, ew1) PHASE2(6, sv1, ew1) PHASE2(7, sv1, ew1)
  }
  for (; j + 8 <= je; j += 8) {
    int svec = ssrc[j + e8];
    float e = as1[(unsigned)svec * 8u + (unsigned)hh] + adp;
    e = fmaxf(e, NEG_SLOPE * e);
    float ew = exp2f(e);
    dsum += ew;
    PHASE2(0, svec, ew) PHASE2(1, svec, ew) PHASE2(2, svec, ew) PHASE2(3, svec, ew)
    PHASE2(4, svec, ew) PHASE2(5, svec, ew) PHASE2(6, svec, ew) PHASE2(7, svec, ew)
  }
  int rem = je - j;
  if (rem > 0) {
    int jj = j + (e8 < rem ? e8 : 0);
    int svec = ssrc[jj];
    float e = as1[(unsigned)svec * 8u + (unsigned)hh] + adp;
    e = fmaxf(e, NEG_SLOPE * e);
    float ew = (e8 < rem) ? exp2f(e) : 0.f;
    dsum += ew;
    for (int k = 0; k < rem; ++k) {
      unsigned sk = (unsigned)__builtin_amdgcn_readlane(svec, k * 8);
      float ewk = __uint_as_float(
          __builtin_amdgcn_ds_bpermute(h2_4 + (k << 5), __float_as_uint(ew)));
      unsigned u8 = *(const unsigned short*)(h1c + ((size_t)sk << 7) + l2);
      a0 += ewk * __builtin_amdgcn_cvt_f32_fp8(u8, 0);
      a1 += ewk * __builtin_amdgcn_cvt_f32_fp8(u8, 1);
    }
  }
#undef PHASE2

  dsum += __shfl_xor(dsum, 8, 64);
  dsum += __shfl_xor(dsum, 16, 64);
  dsum += __shfl_xor(dsum, 32, 64);
  float denom = __uint_as_float(
      __builtin_amdgcn_ds_bpermute(h2_4, __float_as_uint(dsum)));

  float inv = 1.f / (denom + 1e-16f);
  unsigned uid = identb[(unsigned)n * 64u + (unsigned)l];
  float o0 = a0 * inv + bb0;
  float o1 = a1 * inv + bb1;
  o0 = (o0 - mn0) * sc0 + bt0;
  o1 = (o1 - mn1) * sc1 + bt1;
  o0 = o0 > 0.f ? o0 : expm1f(o0);
  o1 = o1 > 0.f ? o1 : expm1f(o1);
  o0 += bf_lo(uid); o1 += bf_hi(uid);
  hpostb[(unsigned)n * 64u + (unsigned)l] = pack2bf(o0, o1);
}

// ---------------------------------------------------------------------------
// MFMA GEMM2, LDS-free. h2b rows padded to 128 B (one line per edge gather).
// ---------------------------------------------------------------------------
__global__ __launch_bounds__(256) void gemm2_kernel(
    const unsigned* __restrict__ hpostb, const float* __restrict__ W2,
    const float* __restrict__ M2ext,
    unsigned* __restrict__ h2b, float* __restrict__ as2, float* __restrict__ ad2, int N)
{
  const int t = threadIdx.x;
  const int l = t & 63, wave = t >> 6;
  const int lx = l & 15, ly = l >> 4;
  const int row0 = blockIdx.x * 128;

  short8 b[3][4];
  short8 b4[4];
  {
    #pragma unroll
    for (int nf = 0; nf < 3; ++nf) {
      int col = nf * 16 + lx;
      bool v = col < 40;
      const float* bp = W2 + (v ? col : 0);
      #pragma unroll
      for (int kf = 0; kf < 4; ++kf) {
        int k0 = kf * 32 + ly * 8;
        U8 f;
        if (v) {
          f.u.x = pack2bf(bp[(k0 + 0) * 40], bp[(k0 + 1) * 40]);
          f.u.y = pack2bf(bp[(k0 + 2) * 40], bp[(k0 + 3) * 40]);
          f.u.z = pack2bf(bp[(k0 + 4) * 40], bp[(k0 + 5) * 40]);
          f.u.w = pack2bf(bp[(k0 + 6) * 40], bp[(k0 + 7) * 40]);
        } else {
          f.u = make_uint4(0, 0, 0, 0);
        }
        b[nf][kf] = f.s;
      }
    }
    bool va = lx < 2;
    const float* bp = M2ext + (va ? lx : 0);
    #pragma unroll
    for (int kf = 0; kf < 4; ++kf) {
      int k0 = kf * 32 + ly * 8;
      U8 f;
      if (va) {
        f.u.x = pack2bf(bp[(k0 + 0) * 2], bp[(k0 + 1) * 2]);
        f.u.y = pack2bf(bp[(k0 + 2) * 2], bp[(k0 + 3) * 2]);
        f.u.z = pack2bf(bp[(k0 + 4) * 2], bp[(k0 + 5) * 2]);
        f.u.w = pack2bf(bp[(k0 + 6) * 2], bp[(k0 + 7) * 2]);
      } else {
        f.u = make_uint4(0, 0, 0, 0);
      }
      b4[kf] = f.s;
    }
  }

  #pragma unroll
  for (int i2 = 0; i2 < 2; ++i2) {
    int mf = wave * 2 + i2;
    int arow = row0 + mf * 16 + lx;
    short8 a[4];
    #pragma unroll
    for (int kf = 0; kf < 4; ++kf) {
      U8 f;
      f.u = make_uint4(0, 0, 0, 0);
      if (arow < N)
        f.u = *(const uint4*)(hpostb + (unsigned)arow * 64u + (unsigned)(kf * 16 + ly * 4));
      a[kf] = f.s;
    }

    int rbase = row0 + mf * 16 + ly * 4;

    #pragma unroll
    for (int nf = 0; nf < 3; ++nf) {
      f32x4 acc = {0.f, 0.f, 0.f, 0.f};
      #pragma unroll
      for (int kf = 0; kf < 4; ++kf)
        acc = __builtin_amdgcn_mfma_f32_16x16x32_bf16(a[kf], b[nf][kf], acc, 0, 0, 0);
      int c = nf * 16 + lx;
      #pragma unroll
      for (int reg = 0; reg < 4; ++reg) {
        float v = acc[reg];
        float vp = __shfl_xor(v, 1, 64);
        int r = rbase + reg;
        if (r < N && c < 40 && !(lx & 1))
          h2b[((unsigned)r << 5) + (unsigned)(c >> 1)] = pack2bf(v, vp);
      }
    }
    {
      f32x4 acc = {0.f, 0.f, 0.f, 0.f};
      #pragma unroll
      for (int kf = 0; kf < 4; ++kf)
        acc = __builtin_amdgcn_mfma_f32_16x16x32_bf16(a[kf], b4[kf], acc, 0, 0, 0);
      #pragma unroll
      for (int reg = 0; reg < 4; ++reg) {
        int r = rbase + reg;
        if (r < N) {
          if (lx == 0) as2[r] = acc[reg];
          else if (lx == 1) ad2[r] = acc[reg];
        }
      }
    }
  }
}

// ---------------------------------------------------------------------------
// Layer-2 aggregation + bias2 + fused log_softmax. 3 edge-groups of 20 lanes,
// x3 unrolled (9 edges in flight); 128-B-aligned h2 rows; exp2 weights.
// ---------------------------------------------------------------------------
__global__ __launch_bounds__(256) void agg2_kernel(
    const int* __restrict__ starts, const int* __restrict__ ends,
    const int* __restrict__ ssrc,
    const float* __restrict__ as2, const float* __restrict__ ad2,
    const unsigned* __restrict__ h2b, const float* __restrict__ bias2,
    float* __restrict__ outp, int N)
{
  const int w = threadIdx.x >> 6, l = threadIdx.x & 63;
  const int n = blockIdx.x * 4 + w;
  if (n >= N) return;
  const int g = l / 20;            // 0,1,2 (3 for idle lanes)
  const int cl = l - g * 20;       // channel pair 0..19
  const unsigned cl4 = (unsigned)(cl * 4);
  const bool act = l < 60;
  const float ad = ad2[n];         // prescaled
  const int jb = starts[n], je = ends[n];

  const char* as2c = (const char*)as2;
  const char* h2c = (const char*)h2b;

  float denom = 0.f, a0 = 0.f, a1 = 0.f;

#define EDGE2(JJ, GUARD) { \
    bool v = act && (GUARD); \
    unsigned s = v ? (unsigned)ssrc[JJ] : 0u; \
    float e = *(const float*)(as2c + (s << 2)) + ad; \
    e = fmaxf(e, NEG_SLOPE * e); \
    float ex = v ? exp2f(e) : 0.f; \
    unsigned u = *(const unsigned*)(h2c + ((size_t)s << 7) + cl4); \
    denom += ex; \
    a0 += ex * bf_lo(u); \
    a1 += ex * bf_hi(u); }

  int j = jb;
  for (; j + 9 <= je; j += 9) {
    EDGE2(j + g, true)
    EDGE2(j + 3 + g, true)
    EDGE2(j + 6 + g, true)
  }
  for (; j < je; j += 3) {
    EDGE2(j + g, (j + g) < je)
  }
#undef EDGE2

  a0 += __shfl(a0, l + 20, 64) + __shfl(a0, l + 40, 64);
  a1 += __shfl(a1, l + 20, 64) + __shfl(a1, l + 40, 64);
  denom += __shfl(denom, l + 20, 64) + __shfl(denom, l + 40, 64);

  const int lc = l < 20 ? l : 0;
  float inv = 1.f / (denom + 1e-16f);
  float o0 = a0 * inv + bias2[2 * lc];
  float o1 = a1 * inv + bias2[2 * lc + 1];

  float mx = wave_max64(l < 20 ? fmaxf(o0, o1) : -3.4e38f);
  float se = wave_sum64(l < 20 ? __expf(o0 - mx) + __expf(o1 - mx) : 0.f);
  float ls = logf(se);
  if (l < 20)
    *(float2*)&outp[(size_t)n * 40 + 2 * l] = make_float2(o0 - mx - ls, o1 - mx - ls);
}

// ---------------------------------------------------------------------------
extern "C" void kernel_launch(void* const* d_in, const int* in_sizes, int n_in,
                              void* d_out, int out_size, void* d_ws, size_t ws_size,
                              hipStream_t stream)
{
  const float* x        = (const float*)d_in[0];
  const int*   ei       = (const int*)d_in[1];
  const float* W1       = (const float*)d_in[2];
  const float* att_src1 = (const float*)d_in[3];
  const float* att_dst1 = (const float*)d_in[4];
  const float* bias1    = (const float*)d_in[5];
  const float* bn_gamma = (const float*)d_in[6];
  const float* bn_beta  = (const float*)d_in[7];
  const float* bn_mean  = (const float*)d_in[8];
  const float* bn_var   = (const float*)d_in[9];
  const float* W2       = (const float*)d_in[10];
  const float* att_src2 = (const float*)d_in[11];
  const float* att_dst2 = (const float*)d_in[12];
  const float* bias2    = (const float*)d_in[13];
  const float* W_skip   = (const float*)d_in[14];
  const float* b_skip   = (const float*)d_in[15];

  const int N = in_sizes[0] / 128;
  const int E = in_sizes[1] / 2;
  const int T = E + N;
  const int NB = (N + BMASK) >> BSH;   // 196

  char* p = (char*)d_ws;
  auto alloc = [&](size_t bytes) { char* q = p; p += (bytes + 255) & ~255ull; return q; };
  unsigned short* h1f8 = (unsigned short*)alloc((size_t)N * 128);   // fp8 [N][128]
  unsigned* hpostb = (unsigned*)alloc((size_t)N * 64 * 4);          // bf16 [N][128]
  unsigned* identb = (unsigned*)alloc((size_t)N * 64 * 4);          // bf16 [N][128]
  float* as1     = (float*)alloc((size_t)N * 8 * 4);
  float* ad1     = (float*)alloc((size_t)N * 8 * 4);
  float* Mext    = (float*)alloc(128 * 16 * 4);
  float* M2ext   = (float*)alloc(128 * 2 * 4);
  int*   starts  = (int*)alloc((size_t)N * 4);
  int*   ends    = (int*)alloc((size_t)N * 4);
  unsigned* pkbuf= (unsigned*)alloc((size_t)NB * BCAP * 4);
  int*   ssrc    = (int*)alloc((size_t)NB * BCAP * 4);
  int*   bcur    = (int*)alloc((size_t)NB * 4);
  // layer-2 reuse of dead layer-1 buffers (h1f8/as1/ad1 dead after agg1)
  unsigned* h2b = (unsigned*)h1f8;   // [N][32] uints = N*128 B, exact fit
  float* as2 = as1;
  float* ad2 = ad1;

  const int* ei_src = ei;
  const int* ei_dst = ei + E;

  hipMemsetAsync(bcur, 0, (size_t)NB * 4, stream);

  prep_kernel<<<1, 128, 0, stream>>>(W1, att_src1, att_dst1, Mext,
                                     W2, att_src2, att_dst2, M2ext);

  const int G1 = (N + 127) / 128;
  const int NBLK_A = 512;
  const int chunk = (T + NBLK_A - 1) / NBLK_A;
  gemm1_scatter_kernel<<<G1 + NBLK_A, 256, 0, stream>>>(
      x, W1, W_skip, b_skip, Mext, h1f8, identb, as1, ad1, N,
      ei_src, ei_dst, bcur, pkbuf, E, T, chunk, NB, G1);

  passB_kernel<<<NB, 256, 0, stream>>>(pkbuf, bcur, starts, ends, ssrc, N);

  agg1_kernel<<<(N + 3) / 4, 256, 0, stream>>>(starts, ends, ssrc, as1, ad1, h1f8,
                                               bias1, bn_gamma, bn_beta, bn_mean, bn_var,
                                               identb, hpostb, N);
  gemm2_kernel<<<(N + 127) / 128, 256, 0, stream>>>(hpostb, W2, M2ext,
                                                    h2b, as2, ad2, N);
  agg2_kernel<<<(N + 3) / 4, 256, 0, stream>>>(starts, ends, ssrc, as2, ad2, h2b, bias2,
                                               (float*)d_out, N);
}

// Round 11
// 248.883 us; speedup vs baseline: 1.4340x; 1.0382x over previous
//
#include <hip/hip_runtime.h>
#include <math.h>

#define NEG_SLOPE 0.2f
#define BN_EPS 1e-5f
#define BSH 9
#define BMASK 511
#define LOG2E 1.44269504088896f
#define BCAP 12288

typedef __attribute__((ext_vector_type(8))) short short8;
typedef __attribute__((ext_vector_type(4))) float f32x4;

__device__ __forceinline__ float wave_max64(float v) {
  #pragma unroll
  for (int o = 32; o; o >>= 1) v = fmaxf(v, __shfl_xor(v, o, 64));
  return v;
}
__device__ __forceinline__ float wave_sum64(float v) {
  #pragma unroll
  for (int o = 32; o; o >>= 1) v += __shfl_xor(v, o, 64);
  return v;
}

__device__ __forceinline__ unsigned pack2bf(float a, float b) {
  unsigned ua = __float_as_uint(a);
  unsigned ub = __float_as_uint(b);
  ua = ua + 0x7fffu + ((ua >> 16) & 1u);
  ub = ub + 0x7fffu + ((ub >> 16) & 1u);
  return (ua >> 16) | (ub & 0xffff0000u);
}
__device__ __forceinline__ float bf_lo(unsigned u) { return __uint_as_float(u << 16); }
__device__ __forceinline__ float bf_hi(unsigned u) { return __uint_as_float(u & 0xffff0000u); }

union U8 { short8 s; uint4 u; };

// ---------------------------------------------------------------------------
// prep: Mext[k][0..7]=W1[k]·att_s per head, [8..15] att_d  (PRESCALED by log2e)
//       M2ext[k][0]=W2[k]·att_s2, [1]=W2[k]·att_d2        (PRESCALED by log2e)
// ---------------------------------------------------------------------------
__global__ void prep_kernel(const float* __restrict__ W1,
                            const float* __restrict__ att_s,
                            const float* __restrict__ att_d,
                            float* __restrict__ Mext,
                            const float* __restrict__ W2,
                            const float* __restrict__ att_s2,
                            const float* __restrict__ att_d2,
                            float* __restrict__ M2ext)
{
  int k = threadIdx.x;   // 0..127
  #pragma unroll
  for (int h = 0; h < 8; ++h) {
    float s = 0.f, d = 0.f;
    #pragma unroll
    for (int c = 0; c < 16; ++c) {
      float w = W1[k * 128 + h * 16 + c];
      s += w * att_s[h * 16 + c];
      d += w * att_d[h * 16 + c];
    }
    Mext[k * 16 + h] = s * LOG2E;
    Mext[k * 16 + 8 + h] = d * LOG2E;
  }
  float s2 = 0.f, d2 = 0.f;
  #pragma unroll
  for (int c = 0; c < 40; ++c) {
    float w = W2[k * 40 + c];
    s2 += w * att_s2[c];
    d2 += w * att_d2[c];
  }
  M2ext[k * 2] = s2 * LOG2E;
  M2ext[k * 2 + 1] = d2 * LOG2E;
}

// ---------------------------------------------------------------------------
// FUSED gemm1 + scatterA. Blocks [0,G1) run the MFMA layer-1 GEMM;
// blocks [G1, G1+512) run the fixed-capacity bucket scatter.
// ---------------------------------------------------------------------------
__global__ __launch_bounds__(256) void gemm1_scatter_kernel(
    const float* __restrict__ X, const float* __restrict__ W1,
    const float* __restrict__ Wsk, const float* __restrict__ bsk,
    const float* __restrict__ Mext,
    unsigned short* __restrict__ h1f8, unsigned* __restrict__ identb,
    float* __restrict__ alpha_s, float* __restrict__ alpha_d, int N,
    const int* __restrict__ esrc, const int* __restrict__ edst,
    int* __restrict__ bcur, unsigned* __restrict__ pkbuf,
    int E, int T, int chunk, int NB, int G1)
{
  __shared__ uint4 Asm4[2048];           // 32 KB (gemm1 tile / scatter scratch)
  const int t = threadIdx.x;

  if ((int)blockIdx.x >= G1) {
    // -------------------- scatter path --------------------
    int* hist  = (int*)Asm4;
    int* lbase = hist + 256;
    int* lcur  = hist + 512;
    const int bid = (int)blockIdx.x - G1;
    hist[t] = 0;
    __syncthreads();
    int s0 = bid * chunk;
    int s1 = min(s0 + chunk, T);
    for (int i = s0 + t; i < s1; i += 256) {
      int d = (i < E) ? edst[i] : (i - E);
      atomicAdd(&hist[d >> BSH], 1);
    }
    __syncthreads();
    if (t < NB) {
      int h = hist[t];
      lbase[t] = t * BCAP + (h ? atomicAdd(&bcur[t], h) : 0);
      lcur[t] = 0;
    }
    __syncthreads();
    for (int i = s0 + t; i < s1; i += 256) {
      int d, s;
      if (i < E) { d = edst[i]; s = esrc[i]; } else { d = s = i - E; }
      int b = d >> BSH;
      int p = lbase[b] + atomicAdd(&lcur[b], 1);
      pkbuf[p] = ((unsigned)(d & BMASK) << 17) | (unsigned)s;
    }
    return;
  }

  // -------------------- gemm1 path --------------------
  const int l = t & 63, wave = t >> 6;
  const int lx = l & 15, ly = l >> 4;
  const int row0 = blockIdx.x * 128;
  const int wn0 = wave * 64;

  short8 b[4][4];
  short8 b4[4] = {};
  #pragma unroll
  for (int nf = 0; nf < 4; ++nf) {
    int c = wn0 + nf * 16 + lx;
    const float* bp = (c < 128) ? (W1 + c) : (Wsk + c - 128);
    #pragma unroll
    for (int kf = 0; kf < 4; ++kf) {
      int k0 = kf * 32 + ly * 8;
      U8 f;
      f.u.x = pack2bf(bp[(k0 + 0) * 128], bp[(k0 + 1) * 128]);
      f.u.y = pack2bf(bp[(k0 + 2) * 128], bp[(k0 + 3) * 128]);
      f.u.z = pack2bf(bp[(k0 + 4) * 128], bp[(k0 + 5) * 128]);
      f.u.w = pack2bf(bp[(k0 + 6) * 128], bp[(k0 + 7) * 128]);
      b[nf][kf] = f.s;
    }
  }
  if (wave == 0) {
    const float* bp = Mext + lx;
    #pragma unroll
    for (int kf = 0; kf < 4; ++kf) {
      int k0 = kf * 32 + ly * 8;
      U8 f;
      f.u.x = pack2bf(bp[(k0 + 0) * 16], bp[(k0 + 1) * 16]);
      f.u.y = pack2bf(bp[(k0 + 2) * 16], bp[(k0 + 3) * 16]);
      f.u.z = pack2bf(bp[(k0 + 4) * 16], bp[(k0 + 5) * 16]);
      f.u.w = pack2bf(bp[(k0 + 6) * 16], bp[(k0 + 7) * 16]);
      b4[kf] = f.s;
    }
  }

  {
    int rl = t >> 1;
    int half = t & 1;
    int r = row0 + rl;
    const float* xp = X + (size_t)r * 128 + half * 64;
    #pragma unroll
    for (int i = 0; i < 8; ++i) {
      float4 f0 = make_float4(0.f, 0.f, 0.f, 0.f), f1 = f0;
      if (r < N) {
        f0 = *(const float4*)(xp + i * 8);
        f1 = *(const float4*)(xp + i * 8 + 4);
      }
      uint4 u;
      u.x = pack2bf(f0.x, f0.y); u.y = pack2bf(f0.z, f0.w);
      u.z = pack2bf(f1.x, f1.y); u.w = pack2bf(f1.z, f1.w);
      int woff = (rl * 256 + half * 128 + i * 16) ^ ((rl & 7) << 4);
      *(uint4*)((char*)Asm4 + woff) = u;
    }
  }
  __syncthreads();

  float bval[4];
  if (wave >= 2) {
    #pragma unroll
    for (int nf = 0; nf < 4; ++nf) bval[nf] = bsk[(wave - 2) * 64 + nf * 16 + lx];
  }

  for (int mf = 0; mf < 8; ++mf) {
    short8 a[4];
    int rowl = mf * 16 + lx;
    #pragma unroll
    for (int kf = 0; kf < 4; ++kf)
      a[kf] = *(short8*)((char*)Asm4 + ((rowl * 256 + kf * 64 + ly * 16) ^ ((lx & 7) << 4)));

    int rbase = row0 + mf * 16 + ly * 4;

    #pragma unroll
    for (int nf = 0; nf < 4; ++nf) {
      f32x4 acc = {0.f, 0.f, 0.f, 0.f};
      #pragma unroll
      for (int kf = 0; kf < 4; ++kf)
        acc = __builtin_amdgcn_mfma_f32_16x16x32_bf16(a[kf], b[nf][kf], acc, 0, 0, 0);
      if (wave < 2) {
        int c = wn0 + nf * 16 + lx;       // even-lane pairs (c, c+1)
        #pragma unroll
        for (int reg = 0; reg < 4; ++reg) {
          float v = acc[reg];
          float vp = __shfl_xor(v, 1, 64);
          int r = rbase + reg;
          if (!(lx & 1) && r < N) {
            int u = __builtin_amdgcn_cvt_pk_fp8_f32(v, vp, 0, false);
            *(unsigned short*)((char*)h1f8 + (unsigned)r * 128u + (unsigned)c) =
                (unsigned short)u;
          }
        }
      } else {
        int c = (wave - 2) * 64 + nf * 16 + lx;
        #pragma unroll
        for (int reg = 0; reg < 4; ++reg) {
          float v = acc[reg] + bval[nf];
          float vp = __shfl_xor(v, 1, 64);
          int r = rbase + reg;
          if (!(lx & 1) && r < N)
            identb[(unsigned)r * 64u + (unsigned)(c >> 1)] = pack2bf(v, vp);
        }
      }
    }

    if (wave == 0) {
      f32x4 acc = {0.f, 0.f, 0.f, 0.f};
      #pragma unroll
      for (int kf = 0; kf < 4; ++kf)
        acc = __builtin_amdgcn_mfma_f32_16x16x32_bf16(a[kf], b4[kf], acc, 0, 0, 0);
      #pragma unroll
      for (int reg = 0; reg < 4; ++reg) {
        int r = rbase + reg;
        if (r < N) {
          if (lx < 8) alpha_s[(size_t)r * 8 + lx] = acc[reg];
          else        alpha_d[(size_t)r * 8 + (lx - 8)] = acc[reg];
        }
      }
    }
  }
}

// ---------------------------------------------------------------------------
// passB: one block per bucket (fixed base b*BCAP, count from bcur).
// Counting sort of <=512 dst values; emits starts/ends + sorted ssrc.
// ---------------------------------------------------------------------------
__global__ __launch_bounds__(256) void passB_kernel(
    const unsigned* __restrict__ pkbuf, const int* __restrict__ bcnt,
    int* __restrict__ starts, int* __restrict__ ends,
    int* __restrict__ ssrc, int N)
{
  __shared__ int cnt[512];
  __shared__ int ps[256];
  __shared__ int cur[512];
  const int t = threadIdx.x;
  const int b = blockIdx.x;
  const int bs = b * BCAP;
  const int be = bs + bcnt[b];

  cnt[t] = 0; cnt[t + 256] = 0;
  __syncthreads();
  for (int i = bs + t; i < be; i += 256)
    atomicAdd(&cnt[pkbuf[i] >> 17], 1);
  __syncthreads();

  int a = cnt[2 * t], b2 = cnt[2 * t + 1];
  ps[t] = a + b2;
  __syncthreads();
  for (int d = 1; d < 256; d <<= 1) {
    int u = (t >= d) ? ps[t - d] : 0;
    __syncthreads();
    ps[t] += u;
    __syncthreads();
  }
  int excl = ps[t] - (a + b2);
  cur[2 * t] = excl;
  cur[2 * t + 1] = excl + a;
  __syncthreads();

  const int node0 = b << BSH;
  {
    int n0 = node0 + 2 * t, n1 = node0 + 2 * t + 1;
    if (n0 < N) { starts[n0] = bs + cur[2 * t];     ends[n0] = bs + cur[2 * t] + a; }
    if (n1 < N) { starts[n1] = bs + cur[2 * t + 1]; ends[n1] = bs + cur[2 * t + 1] + b2; }
  }
  __syncthreads();

  for (int i = bs + t; i < be; i += 256) {
    unsigned pk = pkbuf[i];
    int d = pk >> 17;
    int p = atomicAdd(&cur[d], 1);
    ssrc[bs + p] = (int)(pk & 0x1FFFFu);
  }
}

// ---------------------------------------------------------------------------
// Layer-1 aggregation, two-phase, 8-deep gather pipeline (round-9 structure:
// the 16-deep variant raised VGPR 32->40 and cost 16% occupancy/BW).
// ---------------------------------------------------------------------------
__global__ __launch_bounds__(256) void agg1_kernel(
    const int* __restrict__ starts, const int* __restrict__ ends,
    const int* __restrict__ ssrc,
    const float* __restrict__ as1, const float* __restrict__ ad1,
    const unsigned short* __restrict__ h1f8,
    const float* __restrict__ bias1, const float* __restrict__ gamma,
    const float* __restrict__ beta, const float* __restrict__ mean,
    const float* __restrict__ var,
    const unsigned* __restrict__ identb, unsigned* __restrict__ hpostb, int N)
{
  const int w = threadIdx.x >> 6, l = threadIdx.x & 63;
  const int n = blockIdx.x * 4 + w;
  if (n >= N) return;
  const int e8 = l >> 3;           // phase-1 edge slot
  const int hh = l & 7;            // phase-1 head
  const int h2_4 = (l >> 3) * 4;   // phase-2 head*4 (bpermute byte idx)
  const int c0 = l * 2;
  const unsigned l2 = (unsigned)(l * 2);
  const float adp = ad1[(unsigned)n * 8u + (unsigned)hh];
  const int jb = starts[n], je = ends[n];

  const float bb0 = bias1[c0], bb1 = bias1[c0 + 1];
  const float sc0 = gamma[c0] * rsqrtf(var[c0] + BN_EPS);
  const float sc1 = gamma[c0 + 1] * rsqrtf(var[c0 + 1] + BN_EPS);
  const float mn0 = mean[c0], mn1 = mean[c0 + 1];
  const float bt0 = beta[c0], bt1 = beta[c0 + 1];

  const char* h1c = (const char*)h1f8;

  float dsum = 0.f, a0 = 0.f, a1 = 0.f;

#define PHASE2(K, SVEC, EW) { \
    unsigned sk = (unsigned)__builtin_amdgcn_readlane(SVEC, (K) * 8); \
    float ewk = __uint_as_float( \
        __builtin_amdgcn_ds_bpermute(h2_4 + (K) * 32, __float_as_uint(EW))); \
    unsigned u8 = *(const unsigned short*)(h1c + ((size_t)sk << 7) + l2); \
    a0 += ewk * __builtin_amdgcn_cvt_f32_fp8(u8, 0); \
    a1 += ewk * __builtin_amdgcn_cvt_f32_fp8(u8, 1); }

  int j = jb;
  for (; j + 8 <= je; j += 8) {
    int svec = ssrc[j + e8];
    float e = as1[(unsigned)svec * 8u + (unsigned)hh] + adp;
    e = fmaxf(e, NEG_SLOPE * e);
    float ew = exp2f(e);
    dsum += ew;
    PHASE2(0, svec, ew) PHASE2(1, svec, ew) PHASE2(2, svec, ew) PHASE2(3, svec, ew)
    PHASE2(4, svec, ew) PHASE2(5, svec, ew) PHASE2(6, svec, ew) PHASE2(7, svec, ew)
  }
  int rem = je - j;
  if (rem > 0) {
    int jj = j + (e8 < rem ? e8 : 0);
    int svec = ssrc[jj];
    float e = as1[(unsigned)svec * 8u + (unsigned)hh] + adp;
    e = fmaxf(e, NEG_SLOPE * e);
    float ew = (e8 < rem) ? exp2f(e) : 0.f;
    dsum += ew;
    for (int k = 0; k < rem; ++k) {
      unsigned sk = (unsigned)__builtin_amdgcn_readlane(svec, k * 8);
      float ewk = __uint_as_float(
          __builtin_amdgcn_ds_bpermute(h2_4 + (k << 5), __float_as_uint(ew)));
      unsigned u8 = *(const unsigned short*)(h1c + ((size_t)sk << 7) + l2);
      a0 += ewk * __builtin_amdgcn_cvt_f32_fp8(u8, 0);
      a1 += ewk * __builtin_amdgcn_cvt_f32_fp8(u8, 1);
    }
  }
#undef PHASE2

  dsum += __shfl_xor(dsum, 8, 64);
  dsum += __shfl_xor(dsum, 16, 64);
  dsum += __shfl_xor(dsum, 32, 64);
  float denom = __uint_as_float(
      __builtin_amdgcn_ds_bpermute(h2_4, __float_as_uint(dsum)));

  float inv = 1.f / (denom + 1e-16f);
  unsigned uid = identb[(unsigned)n * 64u + (unsigned)l];
  float o0 = a0 * inv + bb0;
  float o1 = a1 * inv + bb1;
  o0 = (o0 - mn0) * sc0 + bt0;
  o1 = (o1 - mn1) * sc1 + bt1;
  o0 = o0 > 0.f ? o0 : expm1f(o0);
  o1 = o1 > 0.f ? o1 : expm1f(o1);
  o0 += bf_lo(uid); o1 += bf_hi(uid);
  hpostb[(unsigned)n * 64u + (unsigned)l] = pack2bf(o0, o1);
}

// ---------------------------------------------------------------------------
// MFMA GEMM2, LDS-free. h2 split: h2a [N][16 uints] (64 B, ch 0..31) and
// h2b2 [N][4 uints] (16 B, ch 32..39) -> smaller gather footprint for agg2.
// ---------------------------------------------------------------------------
__global__ __launch_bounds__(256) void gemm2_kernel(
    const unsigned* __restrict__ hpostb, const float* __restrict__ W2,
    const float* __restrict__ M2ext,
    unsigned* __restrict__ h2a, unsigned* __restrict__ h2b2,
    float* __restrict__ as2, float* __restrict__ ad2, int N)
{
  const int t = threadIdx.x;
  const int l = t & 63, wave = t >> 6;
  const int lx = l & 15, ly = l >> 4;
  const int row0 = blockIdx.x * 128;

  short8 b[3][4];
  short8 b4[4];
  {
    #pragma unroll
    for (int nf = 0; nf < 3; ++nf) {
      int col = nf * 16 + lx;
      bool v = col < 40;
      const float* bp = W2 + (v ? col : 0);
      #pragma unroll
      for (int kf = 0; kf < 4; ++kf) {
        int k0 = kf * 32 + ly * 8;
        U8 f;
        if (v) {
          f.u.x = pack2bf(bp[(k0 + 0) * 40], bp[(k0 + 1) * 40]);
          f.u.y = pack2bf(bp[(k0 + 2) * 40], bp[(k0 + 3) * 40]);
          f.u.z = pack2bf(bp[(k0 + 4) * 40], bp[(k0 + 5) * 40]);
          f.u.w = pack2bf(bp[(k0 + 6) * 40], bp[(k0 + 7) * 40]);
        } else {
          f.u = make_uint4(0, 0, 0, 0);
        }
        b[nf][kf] = f.s;
      }
    }
    bool va = lx < 2;
    const float* bp = M2ext + (va ? lx : 0);
    #pragma unroll
    for (int kf = 0; kf < 4; ++kf) {
      int k0 = kf * 32 + ly * 8;
      U8 f;
      if (va) {
        f.u.x = pack2bf(bp[(k0 + 0) * 2], bp[(k0 + 1) * 2]);
        f.u.y = pack2bf(bp[(k0 + 2) * 2], bp[(k0 + 3) * 2]);
        f.u.z = pack2bf(bp[(k0 + 4) * 2], bp[(k0 + 5) * 2]);
        f.u.w = pack2bf(bp[(k0 + 6) * 2], bp[(k0 + 7) * 2]);
      } else {
        f.u = make_uint4(0, 0, 0, 0);
      }
      b4[kf] = f.s;
    }
  }

  #pragma unroll
  for (int i2 = 0; i2 < 2; ++i2) {
    int mf = wave * 2 + i2;
    int arow = row0 + mf * 16 + lx;
    short8 a[4];
    #pragma unroll
    for (int kf = 0; kf < 4; ++kf) {
      U8 f;
      f.u = make_uint4(0, 0, 0, 0);
      if (arow < N)
        f.u = *(const uint4*)(hpostb + (unsigned)arow * 64u + (unsigned)(kf * 16 + ly * 4));
      a[kf] = f.s;
    }

    int rbase = row0 + mf * 16 + ly * 4;

    #pragma unroll
    for (int nf = 0; nf < 3; ++nf) {
      f32x4 acc = {0.f, 0.f, 0.f, 0.f};
      #pragma unroll
      for (int kf = 0; kf < 4; ++kf)
        acc = __builtin_amdgcn_mfma_f32_16x16x32_bf16(a[kf], b[nf][kf], acc, 0, 0, 0);
      int c = nf * 16 + lx;
      int cp = c >> 1;
      #pragma unroll
      for (int reg = 0; reg < 4; ++reg) {
        float v = acc[reg];
        float vp = __shfl_xor(v, 1, 64);
        int r = rbase + reg;
        if (r < N && c < 40 && !(lx & 1)) {
          unsigned pk = pack2bf(v, vp);
          if (cp < 16) h2a[((unsigned)r << 4) + (unsigned)cp] = pk;
          else         h2b2[((unsigned)r << 2) + (unsigned)(cp - 16)] = pk;
        }
      }
    }
    {
      f32x4 acc = {0.f, 0.f, 0.f, 0.f};
      #pragma unroll
      for (int kf = 0; kf < 4; ++kf)
        acc = __builtin_amdgcn_mfma_f32_16x16x32_bf16(a[kf], b4[kf], acc, 0, 0, 0);
      #pragma unroll
      for (int reg = 0; reg < 4; ++reg) {
        int r = rbase + reg;
        if (r < N) {
          if (lx == 0) as2[r] = acc[reg];
          else if (lx == 1) ad2[r] = acc[reg];
        }
      }
    }
  }
}

// ---------------------------------------------------------------------------
// Layer-2 aggregation + bias2 + fused log_softmax. 3 edge-groups of 20 lanes,
// x3 unrolled; split h2 buffers (per-lane constant base+shift); exp2 weights.
// ---------------------------------------------------------------------------
__global__ __launch_bounds__(256) void agg2_kernel(
    const int* __restrict__ starts, const int* __restrict__ ends,
    const int* __restrict__ ssrc,
    const float* __restrict__ as2, const float* __restrict__ ad2,
    const unsigned* __restrict__ h2a, const unsigned* __restrict__ h2b2,
    const float* __restrict__ bias2,
    float* __restrict__ outp, int N)
{
  const int w = threadIdx.x >> 6, l = threadIdx.x & 63;
  const int n = blockIdx.x * 4 + w;
  if (n >= N) return;
  const int g = l / 20;            // 0,1,2 (3 for idle lanes)
  const int cl = l - g * 20;       // channel pair 0..19
  const bool act = l < 60;
  const float ad = ad2[n];         // prescaled
  const int jb = starts[n], je = ends[n];

  // per-lane gather base: cl<16 -> h2a row (64 B, shift 6), else h2b2 (16 B, shift 4)
  const char* hbase = (cl < 16) ? ((const char*)h2a + (unsigned)cl * 4u)
                                : ((const char*)h2b2 + (unsigned)(cl - 16) * 4u);
  const unsigned hshift = (cl < 16) ? 6u : 4u;
  const char* as2c = (const char*)as2;

  float denom = 0.f, a0 = 0.f, a1 = 0.f;

#define EDGE2(JJ, GUARD) { \
    bool v = act && (GUARD); \
    unsigned s = v ? (unsigned)ssrc[JJ] : 0u; \
    float e = *(const float*)(as2c + (s << 2)) + ad; \
    e = fmaxf(e, NEG_SLOPE * e); \
    float ex = v ? exp2f(e) : 0.f; \
    unsigned u = *(const unsigned*)(hbase + ((size_t)s << hshift)); \
    denom += ex; \
    a0 += ex * bf_lo(u); \
    a1 += ex * bf_hi(u); }

  int j = jb;
  for (; j + 9 <= je; j += 9) {
    EDGE2(j + g, true)
    EDGE2(j + 3 + g, true)
    EDGE2(j + 6 + g, true)
  }
  for (; j < je; j += 3) {
    EDGE2(j + g, (j + g) < je)
  }
#undef EDGE2

  a0 += __shfl(a0, l + 20, 64) + __shfl(a0, l + 40, 64);
  a1 += __shfl(a1, l + 20, 64) + __shfl(a1, l + 40, 64);
  denom += __shfl(denom, l + 20, 64) + __shfl(denom, l + 40, 64);

  const int lc = l < 20 ? l : 0;
  float inv = 1.f / (denom + 1e-16f);
  float o0 = a0 * inv + bias2[2 * lc];
  float o1 = a1 * inv + bias2[2 * lc + 1];

  float mx = wave_max64(l < 20 ? fmaxf(o0, o1) : -3.4e38f);
  float se = wave_sum64(l < 20 ? __expf(o0 - mx) + __expf(o1 - mx) : 0.f);
  float ls = logf(se);
  if (l < 20)
    *(float2*)&outp[(size_t)n * 40 + 2 * l] = make_float2(o0 - mx - ls, o1 - mx - ls);
}

// ---------------------------------------------------------------------------
extern "C" void kernel_launch(void* const* d_in, const int* in_sizes, int n_in,
                              void* d_out, int out_size, void* d_ws, size_t ws_size,
                              hipStream_t stream)
{
  const float* x        = (const float*)d_in[0];
  const int*   ei       = (const int*)d_in[1];
  const float* W1       = (const float*)d_in[2];
  const float* att_src1 = (const float*)d_in[3];
  const float* att_dst1 = (const float*)d_in[4];
  const float* bias1    = (const float*)d_in[5];
  const float* bn_gamma = (const float*)d_in[6];
  const float* bn_beta  = (const float*)d_in[7];
  const float* bn_mean  = (const float*)d_in[8];
  const float* bn_var   = (const float*)d_in[9];
  const float* W2       = (const float*)d_in[10];
  const float* att_src2 = (const float*)d_in[11];
  const float* att_dst2 = (const float*)d_in[12];
  const float* bias2    = (const float*)d_in[13];
  const float* W_skip   = (const float*)d_in[14];
  const float* b_skip   = (const float*)d_in[15];

  const int N = in_sizes[0] / 128;
  const int E = in_sizes[1] / 2;
  const int T = E + N;
  const int NB = (N + BMASK) >> BSH;   // 196

  char* p = (char*)d_ws;
  auto alloc = [&](size_t bytes) { char* q = p; p += (bytes + 255) & ~255ull; return q; };
  unsigned short* h1f8 = (unsigned short*)alloc((size_t)N * 128);   // fp8 [N][128]
  unsigned* hpostb = (unsigned*)alloc((size_t)N * 64 * 4);          // bf16 [N][128]
  unsigned* identb = (unsigned*)alloc((size_t)N * 64 * 4);          // bf16 [N][128]
  float* as1     = (float*)alloc((size_t)N * 8 * 4);
  float* ad1     = (float*)alloc((size_t)N * 8 * 4);
  float* Mext    = (float*)alloc(128 * 16 * 4);
  float* M2ext   = (float*)alloc(128 * 2 * 4);
  int*   starts  = (int*)alloc((size_t)N * 4);
  int*   ends    = (int*)alloc((size_t)N * 4);
  unsigned* pkbuf= (unsigned*)alloc((size_t)NB * BCAP * 4);
  int*   ssrc    = (int*)alloc((size_t)NB * BCAP * 4);
  int*   bcur    = (int*)alloc((size_t)NB * 4);
  // layer-2 reuse of dead layer-1 buffers (h1f8/as1/ad1 dead after agg1)
  unsigned* h2a  = (unsigned*)h1f8;                 // [N][16] uints = N*64 B
  unsigned* h2b2 = (unsigned*)((char*)h1f8 + (size_t)N * 64);  // [N][4] uints
  float* as2 = as1;
  float* ad2 = ad1;

  const int* ei_src = ei;
  const int* ei_dst = ei + E;

  hipMemsetAsync(bcur, 0, (size_t)NB * 4, stream);

  prep_kernel<<<1, 128, 0, stream>>>(W1, att_src1, att_dst1, Mext,
                                     W2, att_src2, att_dst2, M2ext);

  const int G1 = (N + 127) / 128;
  const int NBLK_A = 512;
  const int chunk = (T + NBLK_A - 1) / NBLK_A;
  gemm1_scatter_kernel<<<G1 + NBLK_A, 256, 0, stream>>>(
      x, W1, W_skip, b_skip, Mext, h1f8, identb, as1, ad1, N,
      ei_src, ei_dst, bcur, pkbuf, E, T, chunk, NB, G1);

  passB_kernel<<<NB, 256, 0, stream>>>(pkbuf, bcur, starts, ends, ssrc, N);

  agg1_kernel<<<(N + 3) / 4, 256, 0, stream>>>(starts, ends, ssrc, as1, ad1, h1f8,
                                               bias1, bn_gamma, bn_beta, bn_mean, bn_var,
                                               identb, hpostb, N);
  gemm2_kernel<<<(N + 127) / 128, 256, 0, stream>>>(hpostb, W2, M2ext,
                                                    h2a, h2b2, as2, ad2, N);
  agg2_kernel<<<(N + 3) / 4, 256, 0, stream>>>(starts, ends, ssrc, as2, ad2,
                                               h2a, h2b2, bias2,
                                               (float*)d_out, N);
}